// Round 2
// baseline (1099.565 us; speedup 1.0000x reference)
//
#include <hip/hip_runtime.h>
#include <math.h>

#define BB 4
#define NN 2048
#define KNB 30
#define HH 128
#define FFD 512

struct F3 { float x,y,z; };
__device__ __forceinline__ F3 f3(float a,float b,float c){ F3 r; r.x=a; r.y=b; r.z=c; return r; }
__device__ __forceinline__ F3 sub3(F3 a, F3 b){ return f3(a.x-b.x, a.y-b.y, a.z-b.z); }
__device__ __forceinline__ float dot3(F3 a, F3 b){ return a.x*b.x + a.y*b.y + a.z*b.z; }
__device__ __forceinline__ F3 cross3(F3 a, F3 b){
  return f3(a.y*b.z-a.z*b.y, a.z*b.x-a.x*b.z, a.x*b.y-a.y*b.x);
}
__device__ __forceinline__ F3 nrm3(F3 a){
  float n2 = dot3(a,a);
  if (n2 <= 0.f) return f3(0.f,0.f,0.f);
  float inv = 1.0f/sqrtf(n2);
  return f3(a.x*inv, a.y*inv, a.z*inv);
}
__device__ __forceinline__ float sgnf(float x){ return (x>0.f)?1.f:((x<0.f)?-1.f:0.f); }
__device__ __forceinline__ float geluf(float x){ return 0.5f*x*(1.f+erff(x*0.70710678118654752440f)); }
__device__ __forceinline__ float clip1(float x){
  const float e = 1e-7f;
  return fminf(fmaxf(x, -1.f+e), 1.f-e);
}

__device__ __forceinline__ float blk_sum128(float v, float* red){
  #pragma unroll
  for (int o=32;o>0;o>>=1) v += __shfl_xor(v, o, 64);
  int w = threadIdx.x >> 6;
  __syncthreads();                 // protect red[] from the previous call's readers
  if ((threadIdx.x & 63)==0) red[w]=v;
  __syncthreads();
  return red[0]+red[1];
}

// ---------------- K1: per-node geometry: feat21 + frame Q ----------------
__global__ void k_geom(const float* __restrict__ X, float* __restrict__ Qws,
                       float* __restrict__ featws){
  int t = blockIdx.x*blockDim.x + threadIdx.x;
  if (t >= BB*NN) return;
  int b = t / NN, n = t % NN;
  const float* Xb = X + (size_t)b*NN*12;
  #define LD3(r,a) f3(Xb[((r)*4+(a))*3+0], Xb[((r)*4+(a))*3+1], Xb[((r)*4+(a))*3+2])
  F3 x0=LD3(n,0), x1=LD3(n,1), x2=LD3(n,2), x3=LD3(n,3);
  F3 U[5];
  U[1]=nrm3(sub3(x1,x0));
  U[2]=nrm3(sub3(x2,x1));
  if (n>0){ F3 p = LD3(n-1,2); U[0]=nrm3(sub3(x0,p)); } else U[0]=f3(0.f,0.f,0.f);
  if (n<NN-1){ F3 y0=LD3(n+1,0), y1=LD3(n+1,1); U[3]=nrm3(sub3(y0,x2)); U[4]=nrm3(sub3(y1,y0)); }
  else { U[3]=f3(0.f,0.f,0.f); U[4]=f3(0.f,0.f,0.f); }

  float feat[21];
  #pragma unroll
  for (int tt=0; tt<3; tt++){
    bool valid = (n>0 || tt>0) && (n<NN-1 || tt==0);  // global idx 3n-1+tt in [0, 3N-4]
    if (valid){
      F3 a=U[tt], bv=U[tt+1], c=U[tt+2];
      F3 n0=nrm3(cross3(a,bv)), n1=nrm3(cross3(bv,c));
      float cd = clip1(dot3(n0,n1));
      F3 v = nrm3(cross3(n0,n1));
      float s = sgnf(-dot3(v,bv));
      // D = s*acos(cd): cos(D) = (s==0 ? 1 : cd), sin(D) = s*sqrt(1-cd^2)
      feat[tt]   = (s==0.f) ? 1.f : cd;
      feat[3+tt] = s*sqrtf(fmaxf(1.f-cd*cd, 0.f));
      float ca = clip1(dot3(a,bv));            // A = acos(ca)
      feat[6+tt] = ca;
      feat[9+tt] = sqrtf(fmaxf(1.f-ca*ca, 0.f));
    } else {
      feat[tt]=1.f; feat[3+tt]=0.f; feat[6+tt]=1.f; feat[9+tt]=0.f;
    }
  }
  float Q[9];
  if (n<NN-1){
    F3 b1=nrm3(sub3(U[1],U[2]));
    F3 n0=nrm3(cross3(U[1],U[2]));
    F3 r2=cross3(b1,n0);
    Q[0]=b1.x;Q[1]=b1.y;Q[2]=b1.z;Q[3]=n0.x;Q[4]=n0.y;Q[5]=n0.z;Q[6]=r2.x;Q[7]=r2.y;Q[8]=r2.z;
  } else {
    #pragma unroll
    for (int i=0;i<9;i++) Q[i]=0.f;
  }
  float* qp = Qws + (size_t)t*9;
  #pragma unroll
  for (int i=0;i<9;i++) qp[i]=Q[i];

  feat[12]=0.f; feat[13]=0.f; feat[14]=0.f;   // normalize(atom0-atom0)=normalize(0) -> 0
  F3 d1=sub3(x2,x0), d2=sub3(x3,x0);
  F3 r1 = nrm3(f3(Q[0]*d1.x+Q[1]*d1.y+Q[2]*d1.z,
                  Q[3]*d1.x+Q[4]*d1.y+Q[5]*d1.z,
                  Q[6]*d1.x+Q[7]*d1.y+Q[8]*d1.z));
  F3 r2v= nrm3(f3(Q[0]*d2.x+Q[1]*d2.y+Q[2]*d2.z,
                  Q[3]*d2.x+Q[4]*d2.y+Q[5]*d2.z,
                  Q[6]*d2.x+Q[7]*d2.y+Q[8]*d2.z));
  feat[15]=r1.x; feat[16]=r1.y; feat[17]=r1.z;
  feat[18]=r2v.x; feat[19]=r2v.y; feat[20]=r2v.z;
  float* fp = featws + (size_t)t*21;
  #pragma unroll
  for (int i=0;i<21;i++) fp[i]=feat[i];
  #undef LD3
}

// ---------------- K2: hV = feat21 @ Wv + b ----------------
__global__ void k_hv(const float* __restrict__ featws, const float* __restrict__ Wv,
                     const float* __restrict__ Wvb, float* __restrict__ hVws){
  int node = blockIdx.x; int h = threadIdx.x;
  const float* f = featws + (size_t)node*21;
  float a = Wvb[h];
  #pragma unroll
  for (int j=0;j<21;j++) a += f[j]*Wv[j*HH+h];
  hVws[(size_t)node*HH+h] = a;
}

// ---------------- K3: edge features + hE + 3-layer message MLP + mean ----------------
__launch_bounds__(128, 2)
__global__ void k_msg(const float* __restrict__ X, const int* __restrict__ Eidx,
                      const float* __restrict__ Qws, const float* __restrict__ hVws,
                      const float* __restrict__ We, const float* __restrict__ W1,
                      const float* __restrict__ W2, const float* __restrict__ W3,
                      const float* __restrict__ Web, const float* __restrict__ W1b,
                      const float* __restrict__ W2b, const float* __restrict__ W3b,
                      float* __restrict__ xpre){
  __shared__ __align__(16) float hv_s[HH];
  __shared__ __align__(16) float e_f[KNB*16];
  __shared__ int idx_s[KNB];
  __shared__ __align__(16) float bufA[KNB*HH];
  __shared__ __align__(16) float bufB[KNB*HH];
  __shared__ __align__(16) float colsum[HH];

  int t = blockIdx.x; int b = t / NN, n = t % NN;
  int h = threadIdx.x;
  float hv = hVws[(size_t)t*HH + h];
  hv_s[h] = hv;

  if (h < KNB){
    int j = Eidx[(size_t)t*KNB + h];
    idx_s[h] = j;
    const float* Qs = Qws + (size_t)t*9;
    float q[9];
    #pragma unroll
    for (int i=0;i<9;i++) q[i]=Qs[i];
    const float* Xb = X + (size_t)b*NN*12;
    F3 Xa = f3(Xb[n*12+0], Xb[n*12+1], Xb[n*12+2]);      // self atom0
    const float* Xn = Xb + (size_t)j*12;
    F3 A[4];
    A[0] = f3(Xn[3],  Xn[4],  Xn[5]);    // atom1 (Xn)
    A[1] = f3(Xn[0],  Xn[1],  Xn[2]);    // atom0 (Nn)
    A[2] = f3(Xn[6],  Xn[7],  Xn[8]);    // atom2 (Cn)
    A[3] = f3(Xn[9],  Xn[10], Xn[11]);   // atom3 (On)
    #pragma unroll
    for (int a=0;a<4;a++){
      F3 d = sub3(A[a], Xa);
      F3 w = f3(q[0]*d.x+q[1]*d.y+q[2]*d.z,
                q[3]*d.x+q[4]*d.y+q[5]*d.z,
                q[6]*d.x+q[7]*d.y+q[8]*d.z);
      F3 wn = nrm3(w);
      e_f[h*16 + a*3 + 0] = wn.x;
      e_f[h*16 + a*3 + 1] = wn.y;
      e_f[h*16 + a*3 + 2] = wn.z;
    }
    const float* Qn = Qws + (size_t)(b*NN + j)*9;
    float p[9];
    #pragma unroll
    for (int i=0;i<9;i++) p[i]=Qn[i];
    // R = Q_self^T @ Q_nbr : R[i][l] = sum_m q[3m+i]*p[3m+l]
    float R00=q[0]*p[0]+q[3]*p[3]+q[6]*p[6];
    float R01=q[0]*p[1]+q[3]*p[4]+q[6]*p[7];
    float R02=q[0]*p[2]+q[3]*p[5]+q[6]*p[8];
    float R10=q[1]*p[0]+q[4]*p[3]+q[7]*p[6];
    float R11=q[1]*p[1]+q[4]*p[4]+q[7]*p[7];
    float R12=q[1]*p[2]+q[4]*p[5]+q[7]*p[8];
    float R20=q[2]*p[0]+q[5]*p[3]+q[8]*p[6];
    float R21=q[2]*p[1]+q[5]*p[4]+q[8]*p[7];
    float R22=q[2]*p[2]+q[5]*p[5]+q[8]*p[8];
    float mx = 0.5f*sqrtf(fabsf(1.f+R00-R11-R22));
    float my = 0.5f*sqrtf(fabsf(1.f-R00+R11-R22));
    float mz = 0.5f*sqrtf(fabsf(1.f-R00-R11+R22));
    float qx = sgnf(R21-R12)*mx;
    float qy = sgnf(R02-R20)*my;
    float qz = sgnf(R10-R01)*mz;
    float qw = 0.5f*sqrtf(fmaxf(1.f+R00+R11+R22, 0.f));
    float n2 = qx*qx+qy*qy+qz*qz+qw*qw;
    float inv = (n2>0.f) ? 1.f/sqrtf(n2) : 0.f;
    e_f[h*16+12]=qx*inv; e_f[h*16+13]=qy*inv; e_f[h*16+14]=qz*inv; e_f[h*16+15]=qw*inv;
  }
  __syncthreads();

  // gather neighbor hV rows into bufB
  for (int k2=0;k2<KNB;k2++)
    bufB[k2*HH+h] = hVws[((size_t)(b*NN) + idx_s[k2])*HH + h];

  // hE = e16 @ We + b -> bufA
  float acc[KNB];
  #pragma unroll
  for (int k2=0;k2<KNB;k2++) acc[k2]=0.f;
  #pragma unroll
  for (int j=0;j<16;j+=4){
    float w0=We[(j+0)*HH+h], w1=We[(j+1)*HH+h], w2=We[(j+2)*HH+h], w3=We[(j+3)*HH+h];
    #pragma unroll
    for (int k2=0;k2<KNB;k2++){
      const float4 e4 = *reinterpret_cast<const float4*>(&e_f[k2*16+j]);
      acc[k2] += e4.x*w0 + e4.y*w1 + e4.z*w2 + e4.w*w3;
    }
  }
  float web = Web[h];
  #pragma unroll
  for (int k2=0;k2<KNB;k2++) bufA[k2*HH+h] = acc[k2] + web;
  __syncthreads();

  // c_self = hV_self . W1[0:128, h]
  float cs = 0.f;
  {
    const float* Wlo = W1 + h;
    for (int j=0;j<HH;j+=4){
      float w0=Wlo[(j+0)*HH], w1=Wlo[(j+1)*HH], w2=Wlo[(j+2)*HH], w3=Wlo[(j+3)*HH];
      const float4 v4 = *reinterpret_cast<const float4*>(&hv_s[j]);
      cs += v4.x*w0 + v4.y*w1 + v4.z*w2 + v4.w*w3;
    }
  }
  // m1 accumulation over hE (bufA) and hV_nbr (bufB)
  #pragma unroll
  for (int k2=0;k2<KNB;k2++) acc[k2]=0.f;
  {
    const float* Wm = W1 + 128*HH + h;
    const float* Wh = W1 + 256*HH + h;
    for (int j=0;j<HH;j+=4){
      float m0=Wm[(j+0)*HH], m1w=Wm[(j+1)*HH], m2w=Wm[(j+2)*HH], m3w=Wm[(j+3)*HH];
      float g0=Wh[(j+0)*HH], g1=Wh[(j+1)*HH], g2=Wh[(j+2)*HH], g3=Wh[(j+3)*HH];
      #pragma unroll
      for (int k2=0;k2<KNB;k2++){
        const float4 a4 = *reinterpret_cast<const float4*>(&bufA[k2*HH+j]);
        const float4 b4 = *reinterpret_cast<const float4*>(&bufB[k2*HH+j]);
        acc[k2] += a4.x*m0 + a4.y*m1w + a4.z*m2w + a4.w*m3w
                 + b4.x*g0 + b4.y*g1  + b4.z*g2  + b4.w*g3;
      }
    }
  }
  __syncthreads();
  float b1v = W1b[h];
  #pragma unroll
  for (int k2=0;k2<KNB;k2++) bufA[k2*HH+h] = geluf(cs + acc[k2] + b1v);
  __syncthreads();

  // m2
  #pragma unroll
  for (int k2=0;k2<KNB;k2++) acc[k2]=0.f;
  {
    const float* Wp = W2 + h;
    for (int j=0;j<HH;j+=4){
      float w0=Wp[(j+0)*HH], w1=Wp[(j+1)*HH], w2=Wp[(j+2)*HH], w3=Wp[(j+3)*HH];
      #pragma unroll
      for (int k2=0;k2<KNB;k2++){
        const float4 a4 = *reinterpret_cast<const float4*>(&bufA[k2*HH+j]);
        acc[k2] += a4.x*w0 + a4.y*w1 + a4.z*w2 + a4.w*w3;
      }
    }
  }
  float b2v = W2b[h];
  #pragma unroll
  for (int k2=0;k2<KNB;k2++) bufB[k2*HH+h] = geluf(acc[k2] + b2v);   // bufB reads ended 2 barriers ago
  __syncthreads();

  // colsum over k of m2, then dh = (colsum @ W3)/30 + b3
  float s = 0.f;
  #pragma unroll
  for (int k2=0;k2<KNB;k2++) s += bufB[k2*HH+h];
  colsum[h] = s;
  __syncthreads();
  float msum = 0.f;
  {
    const float* Wp = W3 + h;
    for (int j=0;j<HH;j+=4){
      float w0=Wp[(j+0)*HH], w1=Wp[(j+1)*HH], w2=Wp[(j+2)*HH], w3=Wp[(j+3)*HH];
      const float4 c4 = *reinterpret_cast<const float4*>(&colsum[j]);
      msum += c4.x*w0 + c4.y*w1 + c4.z*w2 + c4.w*w3;
    }
  }
  float dhv = msum*(1.f/30.f) + W3b[h];
  xpre[(size_t)t*HH + h] = hv + dhv;
}

// ---------------- K4: LN1 + FFN + LN2, 8 nodes per block ----------------
#define G4 8
__launch_bounds__(128, 2)
__global__ void k_ffn(const float* __restrict__ xpre, const float* __restrict__ Wi,
                      const float* __restrict__ Wo, const float* __restrict__ Wib,
                      const float* __restrict__ Wob, const float* __restrict__ l1g,
                      const float* __restrict__ l1b, const float* __restrict__ l2g,
                      const float* __restrict__ l2b, float* __restrict__ out){
  __shared__ __align__(16) float hv1[G4*HH];
  __shared__ __align__(16) float ffh[G4*FFD];
  __shared__ float red[2];
  int h = threadIdx.x;
  int base = blockIdx.x*G4;
  float g1=l1g[h], bb1=l1b[h], g2=l2g[h], bb2=l2b[h];
  float y[G4];
  #pragma unroll
  for (int g=0; g<G4; g++){
    float x = xpre[(size_t)(base+g)*HH + h];
    float mean = blk_sum128(x, red)*(1.f/HH);
    float xm = x-mean;
    float var = blk_sum128(xm*xm, red)*(1.f/HH);
    float yv = xm*(1.f/sqrtf(var+1e-5f))*g1 + bb1;
    y[g]=yv; hv1[g*HH+h]=yv;
  }
  __syncthreads();
  #pragma unroll
  for (int tq=0; tq<4; tq++){
    float accf[G4];
    #pragma unroll
    for (int g=0; g<G4; g++) accf[g]=0.f;
    const float* Wp = Wi + h + 128*tq;
    for (int j=0;j<HH;j+=4){
      float w0=Wp[(j+0)*FFD], w1=Wp[(j+1)*FFD], w2=Wp[(j+2)*FFD], w3=Wp[(j+3)*FFD];
      #pragma unroll
      for (int g=0; g<G4; g++){
        const float4 v4 = *reinterpret_cast<const float4*>(&hv1[g*HH+j]);
        accf[g] += v4.x*w0+v4.y*w1+v4.z*w2+v4.w*w3;
      }
    }
    float bi = Wib[h+128*tq];
    #pragma unroll
    for (int g=0; g<G4; g++) ffh[g*FFD + h + 128*tq] = geluf(accf[g]+bi);
  }
  __syncthreads();
  float o[G4];
  #pragma unroll
  for (int g=0; g<G4; g++) o[g]=0.f;
  {
    const float* Wp = Wo + h;
    for (int j=0;j<FFD;j+=4){
      float w0=Wp[(j+0)*HH], w1=Wp[(j+1)*HH], w2=Wp[(j+2)*HH], w3=Wp[(j+3)*HH];
      #pragma unroll
      for (int g=0; g<G4; g++){
        const float4 v4 = *reinterpret_cast<const float4*>(&ffh[g*FFD+j]);
        o[g] += v4.x*w0+v4.y*w1+v4.z*w2+v4.w*w3;
      }
    }
  }
  float bo = Wob[h];
  #pragma unroll
  for (int g=0; g<G4; g++){
    float x2 = y[g] + o[g] + bo;
    float mean = blk_sum128(x2, red)*(1.f/HH);
    float xm = x2-mean;
    float var = blk_sum128(xm*xm, red)*(1.f/HH);
    out[(size_t)(base+g)*HH + h] = xm*(1.f/sqrtf(var+1e-5f))*g2 + bb2;
  }
}

extern "C" void kernel_launch(void* const* d_in, const int* in_sizes, int n_in,
                              void* d_out, int out_size, void* d_ws, size_t ws_size,
                              hipStream_t stream) {
  (void)in_sizes; (void)n_in; (void)out_size; (void)ws_size;
  const float* X   = (const float*)d_in[0];
  const int*   Ei  = (const int*)  d_in[1];
  const float* Wv  = (const float*)d_in[2];
  const float* Wvb = (const float*)d_in[3];
  const float* We  = (const float*)d_in[4];
  const float* Web = (const float*)d_in[5];
  const float* W1  = (const float*)d_in[6];
  const float* W1b = (const float*)d_in[7];
  const float* W2  = (const float*)d_in[8];
  const float* W2b = (const float*)d_in[9];
  const float* W3  = (const float*)d_in[10];
  const float* W3b = (const float*)d_in[11];
  const float* Wi  = (const float*)d_in[12];
  const float* Wib = (const float*)d_in[13];
  const float* Wo  = (const float*)d_in[14];
  const float* Wob = (const float*)d_in[15];
  const float* l1g = (const float*)d_in[16];
  const float* l1b = (const float*)d_in[17];
  const float* l2g = (const float*)d_in[18];
  const float* l2b = (const float*)d_in[19];
  float* out = (float*)d_out;

  float* wsf    = (float*)d_ws;
  float* featws = wsf + 0;        // 8192*21  = 172032
  float* Qws    = wsf + 172032;   // 8192*9   = 73728
  float* hVws   = wsf + 245760;   // 8192*128 = 1048576
  float* xprews = wsf + 1294336;  // 8192*128 = 1048576  (end: 2342912 floats ~ 9.4 MB)

  k_geom<<<dim3(64),       dim3(128), 0, stream>>>(X, Qws, featws);
  k_hv  <<<dim3(BB*NN),    dim3(128), 0, stream>>>(featws, Wv, Wvb, hVws);
  k_msg <<<dim3(BB*NN),    dim3(128), 0, stream>>>(X, Ei, Qws, hVws, We, W1, W2, W3,
                                                   Web, W1b, W2b, W3b, xprews);
  k_ffn <<<dim3(BB*NN/G4), dim3(128), 0, stream>>>(xprews, Wi, Wo, Wib, Wob,
                                                   l1g, l1b, l2g, l2b, out);
}

// Round 3
// 293.541 us; speedup vs baseline: 3.7459x; 3.7459x over previous
//
#include <hip/hip_runtime.h>
#include <math.h>

#define BB 4
#define NN 2048
#define KNB 30
#define HH 128
#define FFD 512

typedef __attribute__((ext_vector_type(4))) float  f32x4;
typedef __attribute__((ext_vector_type(8))) short  s16x8;

struct F3 { float x,y,z; };
__device__ __forceinline__ F3 f3(float a,float b,float c){ F3 r; r.x=a; r.y=b; r.z=c; return r; }
__device__ __forceinline__ F3 sub3(F3 a, F3 b){ return f3(a.x-b.x, a.y-b.y, a.z-b.z); }
__device__ __forceinline__ float dot3(F3 a, F3 b){ return a.x*b.x + a.y*b.y + a.z*b.z; }
__device__ __forceinline__ F3 cross3(F3 a, F3 b){
  return f3(a.y*b.z-a.z*b.y, a.z*b.x-a.x*b.z, a.x*b.y-a.y*b.x);
}
__device__ __forceinline__ F3 nrm3(F3 a){
  float n2 = dot3(a,a);
  if (n2 <= 0.f) return f3(0.f,0.f,0.f);
  float inv = 1.0f/sqrtf(n2);
  return f3(a.x*inv, a.y*inv, a.z*inv);
}
__device__ __forceinline__ float sgnf(float x){ return (x>0.f)?1.f:((x<0.f)?-1.f:0.f); }
__device__ __forceinline__ float clip1(float x){
  const float e = 1e-7f;
  return fminf(fmaxf(x, -1.f+e), 1.f-e);
}
// tanh-gelu, tail-stable: x * 1/(1+exp(-2u)), u = 0.79788456 x (1+0.044715 x^2)
__device__ __forceinline__ float fgelu(float x){
  float u = 0.7978845608f*x*(1.f + 0.044715f*x*x);
  float d = 1.f + __builtin_amdgcn_exp2f(-2.8853900818f*u);
  return x * __builtin_amdgcn_rcpf(d);
}
// f32 -> bf16 bits, RNE
__device__ __forceinline__ short f2bf(float x){
  union { float f; unsigned u; } v; v.f = x;
  unsigned r = v.u + 0x7fffu + ((v.u >> 16) & 1u);
  return (short)(r >> 16);
}
__device__ __forceinline__ float blk_sum128(float v, float* red){
  #pragma unroll
  for (int o=32;o>0;o>>=1) v += __shfl_xor(v, o, 64);
  int w = threadIdx.x >> 6;
  __syncthreads();
  if ((threadIdx.x & 63)==0) red[w]=v;
  __syncthreads();
  return red[0]+red[1];
}

// ---------------- K1: per-node geometry: feat21 + frame Q ----------------
__global__ void k_geom(const float* __restrict__ X, float* __restrict__ Qws,
                       float* __restrict__ featws){
  int t = blockIdx.x*blockDim.x + threadIdx.x;
  if (t >= BB*NN) return;
  int b = t / NN, n = t % NN;
  const float* Xb = X + (size_t)b*NN*12;
  #define LD3(r,a) f3(Xb[((r)*4+(a))*3+0], Xb[((r)*4+(a))*3+1], Xb[((r)*4+(a))*3+2])
  F3 x0=LD3(n,0), x1=LD3(n,1), x2=LD3(n,2), x3=LD3(n,3);
  F3 U[5];
  U[1]=nrm3(sub3(x1,x0));
  U[2]=nrm3(sub3(x2,x1));
  if (n>0){ F3 p = LD3(n-1,2); U[0]=nrm3(sub3(x0,p)); } else U[0]=f3(0.f,0.f,0.f);
  if (n<NN-1){ F3 y0=LD3(n+1,0), y1=LD3(n+1,1); U[3]=nrm3(sub3(y0,x2)); U[4]=nrm3(sub3(y1,y0)); }
  else { U[3]=f3(0.f,0.f,0.f); U[4]=f3(0.f,0.f,0.f); }

  float feat[21];
  #pragma unroll
  for (int tt=0; tt<3; tt++){
    bool valid = (n>0 || tt>0) && (n<NN-1 || tt==0);
    if (valid){
      F3 a=U[tt], bv=U[tt+1], c=U[tt+2];
      F3 n0=nrm3(cross3(a,bv)), n1=nrm3(cross3(bv,c));
      float cd = clip1(dot3(n0,n1));
      F3 v = nrm3(cross3(n0,n1));
      float s = sgnf(-dot3(v,bv));
      feat[tt]   = (s==0.f) ? 1.f : cd;
      feat[3+tt] = s*sqrtf(fmaxf(1.f-cd*cd, 0.f));
      float ca = clip1(dot3(a,bv));
      feat[6+tt] = ca;
      feat[9+tt] = sqrtf(fmaxf(1.f-ca*ca, 0.f));
    } else {
      feat[tt]=1.f; feat[3+tt]=0.f; feat[6+tt]=1.f; feat[9+tt]=0.f;
    }
  }
  float Q[9];
  if (n<NN-1){
    F3 b1=nrm3(sub3(U[1],U[2]));
    F3 n0=nrm3(cross3(U[1],U[2]));
    F3 r2=cross3(b1,n0);
    Q[0]=b1.x;Q[1]=b1.y;Q[2]=b1.z;Q[3]=n0.x;Q[4]=n0.y;Q[5]=n0.z;Q[6]=r2.x;Q[7]=r2.y;Q[8]=r2.z;
  } else {
    #pragma unroll
    for (int i=0;i<9;i++) Q[i]=0.f;
  }
  float* qp = Qws + (size_t)t*9;
  #pragma unroll
  for (int i=0;i<9;i++) qp[i]=Q[i];

  feat[12]=0.f; feat[13]=0.f; feat[14]=0.f;
  F3 d1=sub3(x2,x0), d2=sub3(x3,x0);
  F3 r1 = nrm3(f3(Q[0]*d1.x+Q[1]*d1.y+Q[2]*d1.z,
                  Q[3]*d1.x+Q[4]*d1.y+Q[5]*d1.z,
                  Q[6]*d1.x+Q[7]*d1.y+Q[8]*d1.z));
  F3 r2v= nrm3(f3(Q[0]*d2.x+Q[1]*d2.y+Q[2]*d2.z,
                  Q[3]*d2.x+Q[4]*d2.y+Q[5]*d2.z,
                  Q[6]*d2.x+Q[7]*d2.y+Q[8]*d2.z));
  feat[15]=r1.x; feat[16]=r1.y; feat[17]=r1.z;
  feat[18]=r2v.x; feat[19]=r2v.y; feat[20]=r2v.z;
  float* fp = featws + (size_t)t*21;
  #pragma unroll
  for (int i=0;i<21;i++) fp[i]=feat[i];
  #undef LD3
}

// ---------------- K_fold: Wfold = We@W1mid, bfold = Web@W1mid, W2T bf16 ----------------
__global__ void k_fold(const float* __restrict__ We, const float* __restrict__ Web,
                       const float* __restrict__ W1, const float* __restrict__ W2,
                       float* __restrict__ Wfold, float* __restrict__ bfold,
                       short* __restrict__ w2t){
  int t = blockIdx.x*256 + threadIdx.x;
  if (t < 2048){
    int j = t >> 7, c = t & 127;
    float a = 0.f;
    for (int k=0;k<HH;k++) a += We[j*HH+k]*W1[(HH+k)*HH + c];
    Wfold[t] = a;
  } else if (t < 2176){
    int c = t - 2048;
    float a = 0.f;
    for (int k=0;k<HH;k++) a += Web[k]*W1[(HH+k)*HH + c];
    bfold[c] = a;
  } else if (t < 2176+16384){
    int i = t - 2176;
    int n = i >> 7, k = i & 127;
    w2t[n*HH + k] = f2bf(W2[k*HH + n]);
  }
}

// ---------------- K_pre: hV, S = hV@W1a + b1 + bfold, G = hV@W1c ----------------
__launch_bounds__(128, 4)
__global__ void k_pre(const float* __restrict__ featws, const float* __restrict__ Wv,
                      const float* __restrict__ Wvb, const float* __restrict__ W1,
                      const float* __restrict__ W1b, const float* __restrict__ bfold,
                      float* __restrict__ hVws, float* __restrict__ Sws,
                      float* __restrict__ Gws){
  __shared__ __align__(16) float hvL[8][HH];
  int h = threadIdx.x;
  int base = blockIdx.x*8;
  #pragma unroll
  for (int g=0; g<8; g++){
    const float* f = featws + (size_t)(base+g)*21;
    float a = Wvb[h];
    #pragma unroll
    for (int j=0;j<21;j++) a += f[j]*Wv[j*HH+h];
    hvL[g][h] = a;
    hVws[(size_t)(base+g)*HH + h] = a;
  }
  __syncthreads();
  float bconst = W1b[h] + bfold[h];
  #pragma unroll 2
  for (int g=0; g<8; g++){
    float s = bconst, gg = 0.f;
    const float* Wa = W1 + h;
    const float* Wc = W1 + 256*HH + h;
    for (int j=0;j<HH;j+=4){
      float h0=hvL[g][j], h1=hvL[g][j+1], h2=hvL[g][j+2], h3=hvL[g][j+3];
      s  += h0*Wa[(j+0)*HH] + h1*Wa[(j+1)*HH] + h2*Wa[(j+2)*HH] + h3*Wa[(j+3)*HH];
      gg += h0*Wc[(j+0)*HH] + h1*Wc[(j+1)*HH] + h2*Wc[(j+2)*HH] + h3*Wc[(j+3)*HH];
    }
    Sws[(size_t)(base+g)*HH + h] = s;
    Gws[(size_t)(base+g)*HH + h] = gg;
  }
}

// ---------------- K_msg: edges + layer1 (VALU K=16) + layer2 (MFMA) + colsum + W3 ----------------
#define NPB 4            // nodes per block
#define A2STR 136        // bf16 row stride (272 B): banks spread, 16B-aligned
__launch_bounds__(256, 2)
__global__ void k_msg(const float* __restrict__ X, const int* __restrict__ Eidx,
                      const float* __restrict__ Qws, const float* __restrict__ Sws,
                      const float* __restrict__ Gws, const float* __restrict__ hVws,
                      const float* __restrict__ Wfoldg, const short* __restrict__ w2t,
                      const float* __restrict__ W2b, const float* __restrict__ W3,
                      const float* __restrict__ W3b, float* __restrict__ xpre){
  __shared__ __align__(16) float efL[128*16];    // edge features, slot-rows
  __shared__ __align__(16) float WfoldL[16*HH];
  __shared__ int idxL[128];
  __shared__ __align__(16) short A2s[128*A2STR]; // m1 bf16, padded rows
  __shared__ __align__(16) float csL[NPB*HH];    // per-node column sums

  const int tid = threadIdx.x;
  const int gbase = blockIdx.x*NPB;          // global node index of slot-group 0
  const int b = gbase >> 11;                 // NN = 2048
  const int bofs = b*NN;

  // stage Wfold (2048 floats, 8 per thread)
  #pragma unroll
  for (int i=0;i<8;i++) WfoldL[i*256 + tid] = Wfoldg[i*256 + tid];

  // ---- edge geometry: threads 0..119, one edge each ----
  if (tid < NPB*KNB){
    int nn = tid / KNB;            // local node 0..3
    int kk = tid - nn*KNB;         // neighbor slot 0..29
    int gnode = gbase + nn;
    int n = gnode - bofs;
    int j = Eidx[(size_t)gnode*KNB + kk];
    int r = nn*32 + kk;            // slot row
    idxL[r] = j;
    const float* Qs = Qws + (size_t)gnode*9;
    float q[9];
    #pragma unroll
    for (int i=0;i<9;i++) q[i]=Qs[i];
    const float* Xb = X + (size_t)b*NN*12;
    F3 Xa = f3(Xb[n*12+0], Xb[n*12+1], Xb[n*12+2]);
    const float* Xn = Xb + (size_t)j*12;
    F3 A[4];
    A[0] = f3(Xn[3],  Xn[4],  Xn[5]);
    A[1] = f3(Xn[0],  Xn[1],  Xn[2]);
    A[2] = f3(Xn[6],  Xn[7],  Xn[8]);
    A[3] = f3(Xn[9],  Xn[10], Xn[11]);
    #pragma unroll
    for (int a=0;a<4;a++){
      F3 d = sub3(A[a], Xa);
      F3 w = f3(q[0]*d.x+q[1]*d.y+q[2]*d.z,
                q[3]*d.x+q[4]*d.y+q[5]*d.z,
                q[6]*d.x+q[7]*d.y+q[8]*d.z);
      F3 wn = nrm3(w);
      efL[r*16 + a*3 + 0] = wn.x;
      efL[r*16 + a*3 + 1] = wn.y;
      efL[r*16 + a*3 + 2] = wn.z;
    }
    const float* Qn = Qws + (size_t)(bofs + j)*9;
    float p[9];
    #pragma unroll
    for (int i=0;i<9;i++) p[i]=Qn[i];
    float R00=q[0]*p[0]+q[3]*p[3]+q[6]*p[6];
    float R01=q[0]*p[1]+q[3]*p[4]+q[6]*p[7];
    float R02=q[0]*p[2]+q[3]*p[5]+q[6]*p[8];
    float R10=q[1]*p[0]+q[4]*p[3]+q[7]*p[6];
    float R11=q[1]*p[1]+q[4]*p[4]+q[7]*p[7];
    float R12=q[1]*p[2]+q[4]*p[5]+q[7]*p[8];
    float R20=q[2]*p[0]+q[5]*p[3]+q[8]*p[6];
    float R21=q[2]*p[1]+q[5]*p[4]+q[8]*p[7];
    float R22=q[2]*p[2]+q[5]*p[5]+q[8]*p[8];
    float mx = 0.5f*sqrtf(fabsf(1.f+R00-R11-R22));
    float my = 0.5f*sqrtf(fabsf(1.f-R00+R11-R22));
    float mz = 0.5f*sqrtf(fabsf(1.f-R00-R11+R22));
    float qx = sgnf(R21-R12)*mx;
    float qy = sgnf(R02-R20)*my;
    float qz = sgnf(R10-R01)*mz;
    float qw = 0.5f*sqrtf(fmaxf(1.f+R00+R11+R22, 0.f));
    float n2 = qx*qx+qy*qy+qz*qz+qw*qw;
    float inv = (n2>0.f) ? 1.f/sqrtf(n2) : 0.f;
    efL[r*16+12]=qx*inv; efL[r*16+13]=qy*inv; efL[r*16+14]=qz*inv; efL[r*16+15]=qw*inv;
  }
  __syncthreads();

  // ---- layer 1 (VALU, K=16): m1 = gelu(ef@Wfold + S[self] + G[nbr]) -> A2s bf16 ----
  {
    const int c  = tid & 127;
    const int rh = tid >> 7;                 // row half: rows rh*64 .. rh*64+63
    float wf[16];
    #pragma unroll
    for (int j=0;j<16;j++) wf[j] = WfoldL[j*HH + c];
    float Sv0 = Sws[(size_t)(gbase + rh*2    )*HH + c];
    float Sv1 = Sws[(size_t)(gbase + rh*2 + 1)*HH + c];
    #pragma unroll
    for (int r8=0; r8<8; r8++){
      int rbase = rh*64 + r8*8;
      float gv[8];
      #pragma unroll
      for (int u=0; u<8; u++){
        int r = rbase + u;
        int slot = r & 31;
        int nbr = idxL[r];
        gv[u] = (slot < KNB) ? Gws[(size_t)(bofs + nbr)*HH + c] : 0.f;
      }
      #pragma unroll
      for (int u=0; u<8; u++){
        int r = rbase + u;
        int slot = r & 31;
        short outv = 0;
        if (slot < KNB){
          const float4 e0 = *reinterpret_cast<const float4*>(&efL[r*16 + 0]);
          const float4 e1 = *reinterpret_cast<const float4*>(&efL[r*16 + 4]);
          const float4 e2 = *reinterpret_cast<const float4*>(&efL[r*16 + 8]);
          const float4 e3 = *reinterpret_cast<const float4*>(&efL[r*16 +12]);
          float acc = ((r>>5)&1) ? Sv1 : Sv0;
          acc += gv[u];
          acc += e0.x*wf[0] + e0.y*wf[1] + e0.z*wf[2] + e0.w*wf[3]
               + e1.x*wf[4] + e1.y*wf[5] + e1.z*wf[6] + e1.w*wf[7]
               + e2.x*wf[8] + e2.y*wf[9] + e2.z*wf[10]+ e2.w*wf[11]
               + e3.x*wf[12]+ e3.y*wf[13]+ e3.z*wf[14]+ e3.w*wf[15];
          outv = f2bf(fgelu(acc));
        }
        A2s[r*A2STR + c] = outv;
      }
    }
  }
  __syncthreads();

  // ---- layer 2 (MFMA 16x16x32 bf16): wave w handles node w (rows 32w..32w+31) ----
  {
    const int w  = tid >> 6;
    const int l  = tid & 63;
    const int lr = l & 15;
    const int lg = l >> 4;
    f32x4 Cacc[2][8];
    #pragma unroll
    for (int mt=0; mt<2; mt++)
      #pragma unroll
      for (int nt=0; nt<8; nt++)
        Cacc[mt][nt] = (f32x4){0.f,0.f,0.f,0.f};
    #pragma unroll
    for (int ks=0; ks<4; ks++){
      const int koff = ks*32 + lg*8;
      s16x8 a0 = *reinterpret_cast<const s16x8*>(&A2s[(w*32      + lr)*A2STR + koff]);
      s16x8 a1 = *reinterpret_cast<const s16x8*>(&A2s[(w*32 + 16 + lr)*A2STR + koff]);
      #pragma unroll
      for (int nt=0; nt<8; nt++){
        s16x8 bv = *reinterpret_cast<const s16x8*>(&w2t[(lr + nt*16)*HH + koff]);
        Cacc[0][nt] = __builtin_amdgcn_mfma_f32_16x16x32_bf16(a0, bv, Cacc[0][nt], 0,0,0);
        Cacc[1][nt] = __builtin_amdgcn_mfma_f32_16x16x32_bf16(a1, bv, Cacc[1][nt], 0,0,0);
      }
    }
    // bias + gelu + masked column sum (rows 0..29 of this node)
    #pragma unroll
    for (int nt=0; nt<8; nt++){
      float b2v = W2b[lr + nt*16];
      float part = 0.f;
      #pragma unroll
      for (int mt=0; mt<2; mt++){
        #pragma unroll
        for (int i=0; i<4; i++){
          int row32 = mt*16 + lg*4 + i;
          float v = fgelu(Cacc[mt][nt][i] + b2v);
          if (row32 < KNB) part += v;
        }
      }
      part += __shfl_xor(part, 16, 64);
      part += __shfl_xor(part, 32, 64);
      if (l < 16) csL[w*HH + nt*16 + lr] = part;
    }
  }
  __syncthreads();

  // ---- dh = colsum @ W3 / 30 + b3; xpre = hV + dh ----
  {
    const int h = tid & 127;
    const int half = tid >> 7;
    #pragma unroll
    for (int q2=0; q2<2; q2++){
      int nn = half*2 + q2;
      const float* cs = csL + nn*HH;
      float acc = 0.f;
      for (int j=0;j<HH;j+=4){
        acc += cs[j]  *W3[(j  )*HH+h] + cs[j+1]*W3[(j+1)*HH+h]
             + cs[j+2]*W3[(j+2)*HH+h] + cs[j+3]*W3[(j+3)*HH+h];
      }
      size_t o = (size_t)(gbase + nn)*HH + h;
      xpre[o] = hVws[o] + acc*(1.f/30.f) + W3b[h];
    }
  }
}

// ---------------- K4: LN1 + FFN + LN2, 8 nodes per block ----------------
#define G4 8
__launch_bounds__(128, 2)
__global__ void k_ffn(const float* __restrict__ xpre, const float* __restrict__ Wi,
                      const float* __restrict__ Wo, const float* __restrict__ Wib,
                      const float* __restrict__ Wob, const float* __restrict__ l1g,
                      const float* __restrict__ l1b, const float* __restrict__ l2g,
                      const float* __restrict__ l2b, float* __restrict__ out){
  __shared__ __align__(16) float hv1[G4*HH];
  __shared__ __align__(16) float ffh[G4*FFD];
  __shared__ float red[2];
  int h = threadIdx.x;
  int base = blockIdx.x*G4;
  float g1=l1g[h], bb1=l1b[h], g2=l2g[h], bb2=l2b[h];
  float y[G4];
  #pragma unroll
  for (int g=0; g<G4; g++){
    float x = xpre[(size_t)(base+g)*HH + h];
    float mean = blk_sum128(x, red)*(1.f/HH);
    float xm = x-mean;
    float var = blk_sum128(xm*xm, red)*(1.f/HH);
    float yv = xm*(1.f/sqrtf(var+1e-5f))*g1 + bb1;
    y[g]=yv; hv1[g*HH+h]=yv;
  }
  __syncthreads();
  #pragma unroll
  for (int tq=0; tq<4; tq++){
    float accf[G4];
    #pragma unroll
    for (int g=0; g<G4; g++) accf[g]=0.f;
    const float* Wp = Wi + h + 128*tq;
    for (int j=0;j<HH;j+=4){
      float w0=Wp[(j+0)*FFD], w1=Wp[(j+1)*FFD], w2=Wp[(j+2)*FFD], w3=Wp[(j+3)*FFD];
      #pragma unroll
      for (int g=0; g<G4; g++){
        const float4 v4 = *reinterpret_cast<const float4*>(&hv1[g*HH+j]);
        accf[g] += v4.x*w0+v4.y*w1+v4.z*w2+v4.w*w3;
      }
    }
    float bi = Wib[h+128*tq];
    #pragma unroll
    for (int g=0; g<G4; g++) ffh[g*FFD + h + 128*tq] = fgelu(accf[g]+bi);
  }
  __syncthreads();
  float o[G4];
  #pragma unroll
  for (int g=0; g<G4; g++) o[g]=0.f;
  {
    const float* Wp = Wo + h;
    for (int j=0;j<FFD;j+=4){
      float w0=Wp[(j+0)*HH], w1=Wp[(j+1)*HH], w2=Wp[(j+2)*HH], w3=Wp[(j+3)*HH];
      #pragma unroll
      for (int g=0; g<G4; g++){
        const float4 v4 = *reinterpret_cast<const float4*>(&ffh[g*FFD+j]);
        o[g] += v4.x*w0+v4.y*w1+v4.z*w2+v4.w*w3;
      }
    }
  }
  float bo = Wob[h];
  #pragma unroll
  for (int g=0; g<G4; g++){
    float x2 = y[g] + o[g] + bo;
    float mean = blk_sum128(x2, red)*(1.f/HH);
    float xm = x2-mean;
    float var = blk_sum128(xm*xm, red)*(1.f/HH);
    out[(size_t)(base+g)*HH + h] = xm*(1.f/sqrtf(var+1e-5f))*g2 + bb2;
  }
}

extern "C" void kernel_launch(void* const* d_in, const int* in_sizes, int n_in,
                              void* d_out, int out_size, void* d_ws, size_t ws_size,
                              hipStream_t stream) {
  (void)in_sizes; (void)n_in; (void)out_size; (void)ws_size;
  const float* X   = (const float*)d_in[0];
  const int*   Ei  = (const int*)  d_in[1];
  const float* Wv  = (const float*)d_in[2];
  const float* Wvb = (const float*)d_in[3];
  const float* We  = (const float*)d_in[4];
  const float* Web = (const float*)d_in[5];
  const float* W1  = (const float*)d_in[6];
  const float* W1b = (const float*)d_in[7];
  const float* W2  = (const float*)d_in[8];
  const float* W2b = (const float*)d_in[9];
  const float* W3  = (const float*)d_in[10];
  const float* W3b = (const float*)d_in[11];
  const float* Wi  = (const float*)d_in[12];
  const float* Wib = (const float*)d_in[13];
  const float* Wo  = (const float*)d_in[14];
  const float* Wob = (const float*)d_in[15];
  const float* l1g = (const float*)d_in[16];
  const float* l1b = (const float*)d_in[17];
  const float* l2g = (const float*)d_in[18];
  const float* l2b = (const float*)d_in[19];
  float* out = (float*)d_out;

  float* wsf    = (float*)d_ws;
  float* featws = wsf + 0;        // 172032
  float* Qws    = wsf + 172032;   // 73728
  float* hVws   = wsf + 245760;   // 1048576
  float* Gws    = wsf + 1294336;  // 1048576
  float* Sws    = wsf + 2342912;  // 1048576 (aliased as xpre: each block reads its own
                                  //          S rows before writing same rows as xpre)
  float* xprews = Sws;
  float* Wfold  = wsf + 3391488;  // 2048
  float* bfold  = wsf + 3393536;  // 128
  short* w2t    = (short*)(wsf + 3393664);  // 16384 bf16 = 8192 floats; end 3401856 (~13.6 MB)

  k_geom<<<dim3(64),   dim3(128), 0, stream>>>(X, Qws, featws);
  k_fold<<<dim3(73),   dim3(256), 0, stream>>>(We, Web, W1, W2, Wfold, bfold, w2t);
  k_pre <<<dim3(1024), dim3(128), 0, stream>>>(featws, Wv, Wvb, W1, W1b, bfold,
                                               hVws, Sws, Gws);
  k_msg <<<dim3(BB*NN/NPB), dim3(256), 0, stream>>>(X, Ei, Qws, Sws, Gws, hVws,
                                                    Wfold, w2t, W2b, W3, W3b, xprews);
  k_ffn <<<dim3(BB*NN/G4),  dim3(128), 0, stream>>>(xprews, Wi, Wo, Wib, Wob,
                                                    l1g, l1b, l2g, l2b, out);
}

// Round 5
// 212.891 us; speedup vs baseline: 5.1649x; 1.3788x over previous
//
#include <hip/hip_runtime.h>
#include <math.h>

#define BB 4
#define NN 2048
#define KNB 30
#define HH 128
#define FFD 512

typedef __attribute__((ext_vector_type(4))) float  f32x4;
typedef __attribute__((ext_vector_type(8))) short  s16x8;

struct F3 { float x,y,z; };
__device__ __forceinline__ F3 f3(float a,float b,float c){ F3 r; r.x=a; r.y=b; r.z=c; return r; }
__device__ __forceinline__ F3 sub3(F3 a, F3 b){ return f3(a.x-b.x, a.y-b.y, a.z-b.z); }
__device__ __forceinline__ float dot3(F3 a, F3 b){ return a.x*b.x + a.y*b.y + a.z*b.z; }
__device__ __forceinline__ F3 cross3(F3 a, F3 b){
  return f3(a.y*b.z-a.z*b.y, a.z*b.x-a.x*b.z, a.x*b.y-a.y*b.x);
}
__device__ __forceinline__ F3 nrm3(F3 a){
  float n2 = dot3(a,a);
  if (n2 <= 0.f) return f3(0.f,0.f,0.f);
  float inv = 1.0f/sqrtf(n2);
  return f3(a.x*inv, a.y*inv, a.z*inv);
}
__device__ __forceinline__ float sgnf(float x){ return (x>0.f)?1.f:((x<0.f)?-1.f:0.f); }
__device__ __forceinline__ float clip1(float x){
  const float e = 1e-7f;
  return fminf(fmaxf(x, -1.f+e), 1.f-e);
}
// tanh-gelu, tail-stable: x * 1/(1+exp(-2u)), u = 0.79788456 x (1+0.044715 x^2)
__device__ __forceinline__ float fgelu(float x){
  float u = 0.7978845608f*x*(1.f + 0.044715f*x*x);
  float d = 1.f + __builtin_amdgcn_exp2f(-2.8853900818f*u);
  return x * __builtin_amdgcn_rcpf(d);
}
// f32 -> bf16 bits, RNE
__device__ __forceinline__ short f2bf(float x){
  union { float f; unsigned u; } v; v.f = x;
  unsigned r = v.u + 0x7fffu + ((v.u >> 16) & 1u);
  return (short)(r >> 16);
}

// ---------------- K1: per-node geometry: feat21 + frame Q ----------------
__global__ void k_geom(const float* __restrict__ X, float* __restrict__ Qws,
                       float* __restrict__ featws){
  int t = blockIdx.x*blockDim.x + threadIdx.x;
  if (t >= BB*NN) return;
  int b = t / NN, n = t % NN;
  const float* Xb = X + (size_t)b*NN*12;
  #define LD3(r,a) f3(Xb[((r)*4+(a))*3+0], Xb[((r)*4+(a))*3+1], Xb[((r)*4+(a))*3+2])
  F3 x0=LD3(n,0), x1=LD3(n,1), x2=LD3(n,2), x3=LD3(n,3);
  F3 U[5];
  U[1]=nrm3(sub3(x1,x0));
  U[2]=nrm3(sub3(x2,x1));
  if (n>0){ F3 p = LD3(n-1,2); U[0]=nrm3(sub3(x0,p)); } else U[0]=f3(0.f,0.f,0.f);
  if (n<NN-1){ F3 y0=LD3(n+1,0), y1=LD3(n+1,1); U[3]=nrm3(sub3(y0,x2)); U[4]=nrm3(sub3(y1,y0)); }
  else { U[3]=f3(0.f,0.f,0.f); U[4]=f3(0.f,0.f,0.f); }

  float feat[21];
  #pragma unroll
  for (int tt=0; tt<3; tt++){
    bool valid = (n>0 || tt>0) && (n<NN-1 || tt==0);
    if (valid){
      F3 a=U[tt], bv=U[tt+1], c=U[tt+2];
      F3 n0=nrm3(cross3(a,bv)), n1=nrm3(cross3(bv,c));
      float cd = clip1(dot3(n0,n1));
      F3 v = nrm3(cross3(n0,n1));
      float s = sgnf(-dot3(v,bv));
      feat[tt]   = (s==0.f) ? 1.f : cd;
      feat[3+tt] = s*sqrtf(fmaxf(1.f-cd*cd, 0.f));
      float ca = clip1(dot3(a,bv));
      feat[6+tt] = ca;
      feat[9+tt] = sqrtf(fmaxf(1.f-ca*ca, 0.f));
    } else {
      feat[tt]=1.f; feat[3+tt]=0.f; feat[6+tt]=1.f; feat[9+tt]=0.f;
    }
  }
  float Q[9];
  if (n<NN-1){
    F3 b1=nrm3(sub3(U[1],U[2]));
    F3 n0=nrm3(cross3(U[1],U[2]));
    F3 r2=cross3(b1,n0);
    Q[0]=b1.x;Q[1]=b1.y;Q[2]=b1.z;Q[3]=n0.x;Q[4]=n0.y;Q[5]=n0.z;Q[6]=r2.x;Q[7]=r2.y;Q[8]=r2.z;
  } else {
    #pragma unroll
    for (int i=0;i<9;i++) Q[i]=0.f;
  }
  float* qp = Qws + (size_t)t*9;
  #pragma unroll
  for (int i=0;i<9;i++) qp[i]=Q[i];

  feat[12]=0.f; feat[13]=0.f; feat[14]=0.f;
  F3 d1=sub3(x2,x0), d2=sub3(x3,x0);
  F3 r1 = nrm3(f3(Q[0]*d1.x+Q[1]*d1.y+Q[2]*d1.z,
                  Q[3]*d1.x+Q[4]*d1.y+Q[5]*d1.z,
                  Q[6]*d1.x+Q[7]*d1.y+Q[8]*d1.z));
  F3 r2v= nrm3(f3(Q[0]*d2.x+Q[1]*d2.y+Q[2]*d2.z,
                  Q[3]*d2.x+Q[4]*d2.y+Q[5]*d2.z,
                  Q[6]*d2.x+Q[7]*d2.y+Q[8]*d2.z));
  feat[15]=r1.x; feat[16]=r1.y; feat[17]=r1.z;
  feat[18]=r2v.x; feat[19]=r2v.y; feat[20]=r2v.z;
  float* fp = featws + (size_t)t*21;
  #pragma unroll
  for (int i=0;i<21;i++) fp[i]=feat[i];
  #undef LD3
}

// ---- K_fold: Wfold=We@W1mid, bfold=Web@W1mid, bf16 transposes of W2,W1a,W1c,Wi,Wo ----
__global__ void k_fold(const float* __restrict__ We, const float* __restrict__ Web,
                       const float* __restrict__ W1, const float* __restrict__ W2,
                       const float* __restrict__ Wi, const float* __restrict__ Wo,
                       float* __restrict__ Wfold, float* __restrict__ bfold,
                       short* __restrict__ w2t, short* __restrict__ w1aT,
                       short* __restrict__ w1cT, short* __restrict__ wiT,
                       short* __restrict__ woT){
  int t = blockIdx.x*256 + threadIdx.x;
  if (t < 2048){
    int j = t >> 7, c = t & 127;
    float a = 0.f;
    for (int k=0;k<HH;k++) a += We[j*HH+k]*W1[(HH+k)*HH + c];
    Wfold[t] = a;
  } else if (t < 2176){
    int c = t - 2048;
    float a = 0.f;
    for (int k=0;k<HH;k++) a += Web[k]*W1[(HH+k)*HH + c];
    bfold[c] = a;
  } else if (t < 18560){
    int i = t - 2176;  int n = i >> 7, k = i & 127;
    w2t[n*HH + k] = f2bf(W2[k*HH + n]);
  } else if (t < 34944){
    int i = t - 18560; int n = i >> 7, k = i & 127;
    w1aT[n*HH + k] = f2bf(W1[k*HH + n]);
  } else if (t < 51328){
    int i = t - 34944; int n = i >> 7, k = i & 127;
    w1cT[n*HH + k] = f2bf(W1[(256+k)*HH + n]);
  } else if (t < 116864){
    int i = t - 51328; int n = i >> 7, k = i & 127;   // n 0..511
    wiT[n*HH + k] = f2bf(Wi[k*FFD + n]);
  } else if (t < 182400){
    int i = t - 116864; int k = i >> 7, n = i & 127;  // k 0..511
    woT[n*FFD + k] = f2bf(Wo[k*HH + n]);
  }
}

// ---- K_pre: hV (VALU K=21); S = hV@W1a + b1 + bfold, G = hV@W1c (MFMA) ----
#define PNB 32
__global__ void k_pre(const float* __restrict__ featws, const float* __restrict__ Wv,
                      const float* __restrict__ Wvb, const short* __restrict__ w1aT,
                      const short* __restrict__ w1cT, const float* __restrict__ W1b,
                      const float* __restrict__ bfold, float* __restrict__ hVws,
                      float* __restrict__ Sws, float* __restrict__ Gws){
  __shared__ __align__(16) short hvL[PNB][136];   // bf16, 272B rows
  int tid = threadIdx.x;
  int base = blockIdx.x*PNB;
  {
    int c = tid & 127, half = tid >> 7;
    float wv[21];
    #pragma unroll
    for (int j=0;j<21;j++) wv[j] = Wv[j*HH + c];
    float wb = Wvb[c];
    #pragma unroll 2
    for (int it=0; it<16; ++it){
      int g = it*2 + half;
      const float* f = featws + (size_t)(base+g)*21;
      float a = wb;
      #pragma unroll
      for (int j=0;j<21;j++) a += f[j]*wv[j];
      hVws[(size_t)(base+g)*HH + c] = a;
      hvL[g][c] = f2bf(a);
    }
  }
  __syncthreads();
  {
    int l = tid & 63, w = tid >> 6;
    int lr = l & 15, lg = l >> 4;
    int m = w & 1;                 // M-tile (rows m*16..m*16+15)
    int nbase = (w >> 1)*4;        // 4 N-tiles per wave
    s16x8 afr[4];
    #pragma unroll
    for (int ks=0; ks<4; ks++)
      afr[ks] = *reinterpret_cast<const s16x8*>(&hvL[m*16 + lr][ks*32 + lg*8]);
    f32x4 Cs[4], Cg[4];
    #pragma unroll
    for (int q=0;q<4;q++){ Cs[q]=(f32x4){0,0,0,0}; Cg[q]=(f32x4){0,0,0,0}; }
    #pragma unroll
    for (int q=0;q<4;q++){
      int ncol = (nbase+q)*16 + lr;
      #pragma unroll
      for (int ks=0; ks<4; ks++){
        s16x8 ba = *reinterpret_cast<const s16x8*>(&w1aT[ncol*HH + ks*32 + lg*8]);
        s16x8 bc = *reinterpret_cast<const s16x8*>(&w1cT[ncol*HH + ks*32 + lg*8]);
        Cs[q] = __builtin_amdgcn_mfma_f32_16x16x32_bf16(afr[ks], ba, Cs[q], 0,0,0);
        Cg[q] = __builtin_amdgcn_mfma_f32_16x16x32_bf16(afr[ks], bc, Cg[q], 0,0,0);
      }
    }
    #pragma unroll
    for (int q=0;q<4;q++){
      int ncol = (nbase+q)*16 + lr;
      float bc = W1b[ncol] + bfold[ncol];
      #pragma unroll
      for (int i=0;i<4;i++){
        int row = m*16 + lg*4 + i;
        size_t o = (size_t)(base+row)*HH + ncol;
        Sws[o] = Cs[q][i] + bc;
        Gws[o] = Cg[q][i];
      }
    }
  }
}

// ---------------- K_msg: edges + layer1 (VALU K=16) + layer2 (MFMA) + colsum + W3 ----------------
#define NPB 4            // nodes per block
#define A2STR 136        // bf16 row stride (272 B)
__launch_bounds__(256, 3)
__global__ void k_msg(const float* __restrict__ X, const int* __restrict__ Eidx,
                      const float* __restrict__ Qws, const float* __restrict__ Sws,
                      const float* __restrict__ Gws, const float* __restrict__ hVws,
                      const float* __restrict__ Wfoldg, const short* __restrict__ w2t,
                      const float* __restrict__ W2b, const float* __restrict__ W3,
                      const float* __restrict__ W3b, float* __restrict__ xpre){
  __shared__ __align__(16) float efL[128*16];    // edge features, slot-rows
  __shared__ int idxL[128];
  __shared__ __align__(16) short A2s[128*A2STR]; // m1 bf16, padded rows
  __shared__ __align__(16) float csL[NPB*HH];    // per-node column sums

  const int tid = threadIdx.x;
  const int gbase = blockIdx.x*NPB;
  const int b = gbase >> 11;
  const int bofs = b*NN;

  // ---- edge geometry: threads 0..119, one edge each ----
  if (tid < NPB*KNB){
    int nn = tid / KNB;
    int kk = tid - nn*KNB;
    int gnode = gbase + nn;
    int n = gnode - bofs;
    int j = Eidx[(size_t)gnode*KNB + kk];
    int r = nn*32 + kk;
    idxL[r] = j;
    const float* Qs = Qws + (size_t)gnode*9;
    float q[9];
    #pragma unroll
    for (int i=0;i<9;i++) q[i]=Qs[i];
    const float* Xb = X + (size_t)b*NN*12;
    F3 Xa = f3(Xb[n*12+0], Xb[n*12+1], Xb[n*12+2]);
    const float* Xn = Xb + (size_t)j*12;
    F3 A[4];
    A[0] = f3(Xn[3],  Xn[4],  Xn[5]);
    A[1] = f3(Xn[0],  Xn[1],  Xn[2]);
    A[2] = f3(Xn[6],  Xn[7],  Xn[8]);
    A[3] = f3(Xn[9],  Xn[10], Xn[11]);
    #pragma unroll
    for (int a=0;a<4;a++){
      F3 d = sub3(A[a], Xa);
      F3 w = f3(q[0]*d.x+q[1]*d.y+q[2]*d.z,
                q[3]*d.x+q[4]*d.y+q[5]*d.z,
                q[6]*d.x+q[7]*d.y+q[8]*d.z);
      F3 wn = nrm3(w);
      efL[r*16 + a*3 + 0] = wn.x;
      efL[r*16 + a*3 + 1] = wn.y;
      efL[r*16 + a*3 + 2] = wn.z;
    }
    const float* Qn = Qws + (size_t)(bofs + j)*9;
    float p[9];
    #pragma unroll
    for (int i=0;i<9;i++) p[i]=Qn[i];
    float R00=q[0]*p[0]+q[3]*p[3]+q[6]*p[6];
    float R01=q[0]*p[1]+q[3]*p[4]+q[6]*p[7];
    float R02=q[0]*p[2]+q[3]*p[5]+q[6]*p[8];
    float R10=q[1]*p[0]+q[4]*p[3]+q[7]*p[6];
    float R11=q[1]*p[1]+q[4]*p[4]+q[7]*p[7];
    float R12=q[1]*p[2]+q[4]*p[5]+q[7]*p[8];
    float R20=q[2]*p[0]+q[5]*p[3]+q[8]*p[6];
    float R21=q[2]*p[1]+q[5]*p[4]+q[8]*p[7];
    float R22=q[2]*p[2]+q[5]*p[5]+q[8]*p[8];
    float mx = 0.5f*sqrtf(fabsf(1.f+R00-R11-R22));
    float my = 0.5f*sqrtf(fabsf(1.f-R00+R11-R22));
    float mz = 0.5f*sqrtf(fabsf(1.f-R00-R11+R22));
    float qx = sgnf(R21-R12)*mx;
    float qy = sgnf(R02-R20)*my;
    float qz = sgnf(R10-R01)*mz;
    float qw = 0.5f*sqrtf(fmaxf(1.f+R00+R11+R22, 0.f));
    float n2 = qx*qx+qy*qy+qz*qz+qw*qw;
    float inv = (n2>0.f) ? 1.f/sqrtf(n2) : 0.f;
    efL[r*16+12]=qx*inv; efL[r*16+13]=qy*inv; efL[r*16+14]=qz*inv; efL[r*16+15]=qw*inv;
  }
  __syncthreads();

  // ---- layer 1 (VALU, K=16): m1 = gelu(ef@Wfold + S[self] + G[nbr]) -> A2s bf16 ----
  {
    const int c  = tid & 127;
    const int rh = tid >> 7;
    float wf[16];
    #pragma unroll
    for (int j=0;j<16;j++) wf[j] = Wfoldg[j*HH + c];
    float Sv0 = Sws[(size_t)(gbase + rh*2    )*HH + c];
    float Sv1 = Sws[(size_t)(gbase + rh*2 + 1)*HH + c];
    #pragma unroll
    for (int r8=0; r8<8; r8++){
      int rbase = rh*64 + r8*8;
      float gv[8];
      #pragma unroll
      for (int u=0; u<8; u++){
        int r = rbase + u;
        int slot = r & 31;
        int nbr = idxL[r];
        gv[u] = (slot < KNB) ? Gws[(size_t)(bofs + nbr)*HH + c] : 0.f;
      }
      #pragma unroll
      for (int u=0; u<8; u++){
        int r = rbase + u;
        int slot = r & 31;
        short outv = 0;
        if (slot < KNB){
          const float4 e0 = *reinterpret_cast<const float4*>(&efL[r*16 + 0]);
          const float4 e1 = *reinterpret_cast<const float4*>(&efL[r*16 + 4]);
          const float4 e2 = *reinterpret_cast<const float4*>(&efL[r*16 + 8]);
          const float4 e3 = *reinterpret_cast<const float4*>(&efL[r*16 +12]);
          float acc = ((r>>5)&1) ? Sv1 : Sv0;
          acc += gv[u];
          acc += e0.x*wf[0] + e0.y*wf[1] + e0.z*wf[2] + e0.w*wf[3]
               + e1.x*wf[4] + e1.y*wf[5] + e1.z*wf[6] + e1.w*wf[7]
               + e2.x*wf[8] + e2.y*wf[9] + e2.z*wf[10]+ e2.w*wf[11]
               + e3.x*wf[12]+ e3.y*wf[13]+ e3.z*wf[14]+ e3.w*wf[15];
          outv = f2bf(fgelu(acc));
        }
        A2s[r*A2STR + c] = outv;
      }
    }
  }
  __syncthreads();

  // ---- layer 2 (MFMA 16x16x32 bf16): wave w handles node w ----
  {
    const int w  = tid >> 6;
    const int l  = tid & 63;
    const int lr = l & 15;
    const int lg = l >> 4;
    f32x4 Cacc[2][8];
    #pragma unroll
    for (int mt=0; mt<2; mt++)
      #pragma unroll
      for (int nt=0; nt<8; nt++)
        Cacc[mt][nt] = (f32x4){0.f,0.f,0.f,0.f};
    #pragma unroll
    for (int ks=0; ks<4; ks++){
      const int koff = ks*32 + lg*8;
      s16x8 a0 = *reinterpret_cast<const s16x8*>(&A2s[(w*32      + lr)*A2STR + koff]);
      s16x8 a1 = *reinterpret_cast<const s16x8*>(&A2s[(w*32 + 16 + lr)*A2STR + koff]);
      #pragma unroll
      for (int nt=0; nt<8; nt++){
        s16x8 bv = *reinterpret_cast<const s16x8*>(&w2t[(lr + nt*16)*HH + koff]);
        Cacc[0][nt] = __builtin_amdgcn_mfma_f32_16x16x32_bf16(a0, bv, Cacc[0][nt], 0,0,0);
        Cacc[1][nt] = __builtin_amdgcn_mfma_f32_16x16x32_bf16(a1, bv, Cacc[1][nt], 0,0,0);
      }
    }
    #pragma unroll
    for (int nt=0; nt<8; nt++){
      float b2v = W2b[lr + nt*16];
      float part = 0.f;
      #pragma unroll
      for (int mt=0; mt<2; mt++){
        #pragma unroll
        for (int i=0; i<4; i++){
          int row32 = mt*16 + lg*4 + i;
          float v = fgelu(Cacc[mt][nt][i] + b2v);
          if (row32 < KNB) part += v;
        }
      }
      part += __shfl_xor(part, 16, 64);
      part += __shfl_xor(part, 32, 64);
      if (l < 16) csL[w*HH + nt*16 + lr] = part;
    }
  }
  __syncthreads();

  // ---- dh = colsum @ W3 / 30 + b3; xpre = hV + dh ----
  {
    const int h = tid & 127;
    const int half = tid >> 7;
    #pragma unroll
    for (int q2=0; q2<2; q2++){
      int nn = half*2 + q2;
      const float* cs = csL + nn*HH;
      float acc = 0.f;
      for (int j=0;j<HH;j+=4){
        acc += cs[j]  *W3[(j  )*HH+h] + cs[j+1]*W3[(j+1)*HH+h]
             + cs[j+2]*W3[(j+2)*HH+h] + cs[j+3]*W3[(j+3)*HH+h];
      }
      size_t o = (size_t)(gbase + nn)*HH + h;
      xpre[o] = hVws[o] + acc*(1.f/30.f) + W3b[h];
    }
  }
}

// ---------------- K4: LN1 + FFN (MFMA) + LN2, 16 nodes per block, 4 waves ----------------
#define FNB 16
__global__ void k_ffn(const float* __restrict__ xpre, const short* __restrict__ wiT,
                      const short* __restrict__ woT, const float* __restrict__ Wib,
                      const float* __restrict__ Wob, const float* __restrict__ l1g,
                      const float* __restrict__ l1b, const float* __restrict__ l2g,
                      const float* __restrict__ l2b, float* __restrict__ out){
  __shared__ __align__(16) short hv1[FNB][136];   // bf16 LN1 out
  __shared__ __align__(16) float yL[FNB][HH];     // f32 LN1 out (residual)
  __shared__ __align__(16) short ffh[FNB][520];   // bf16 gelu(ffn1)
  __shared__ float partS[FNB][4], partQ[FNB][4];
  const int tid = threadIdx.x;
  const int l = tid & 63, w = tid >> 6;
  const int base = blockIdx.x*FNB;

  // ---- LN1: wave w owns rows 4w..4w+3; lane l covers cols l, l+64 ----
  #pragma unroll
  for (int ri=0; ri<4; ri++){
    int r = w*4 + ri;
    const float* xp = xpre + (size_t)(base+r)*HH;
    float x0 = xp[l], x1 = xp[l+64];
    float s = x0 + x1;
    #pragma unroll
    for (int o=32;o>0;o>>=1) s += __shfl_xor(s, o, 64);
    float mean = s*(1.f/HH);
    float d0 = x0-mean, d1 = x1-mean;
    float q = d0*d0 + d1*d1;
    #pragma unroll
    for (int o=32;o>0;o>>=1) q += __shfl_xor(q, o, 64);
    float inv = 1.f/sqrtf(q*(1.f/HH) + 1e-5f);
    float y0 = d0*inv*l1g[l]    + l1b[l];
    float y1 = d1*inv*l1g[l+64] + l1b[l+64];
    yL[r][l] = y0; yL[r][l+64] = y1;
    hv1[r][l] = f2bf(y0); hv1[r][l+64] = f2bf(y1);
  }
  __syncthreads();

  const int lr = l & 15, lg = l >> 4;
  // ---- GEMM1: [16x128]@WiT -> gelu -> ffh bf16. wave w: N-tiles w*8..w*8+7 ----
  {
    s16x8 afr[4];
    #pragma unroll
    for (int ks=0; ks<4; ks++)
      afr[ks] = *reinterpret_cast<const s16x8*>(&hv1[lr][ks*32 + lg*8]);
    #pragma unroll
    for (int q=0; q<8; q++){
      int ncol = (w*8+q)*16 + lr;
      f32x4 C = (f32x4){0,0,0,0};
      #pragma unroll
      for (int ks=0; ks<4; ks++){
        s16x8 bv = *reinterpret_cast<const s16x8*>(&wiT[ncol*HH + ks*32 + lg*8]);
        C = __builtin_amdgcn_mfma_f32_16x16x32_bf16(afr[ks], bv, C, 0,0,0);
      }
      float bi = Wib[ncol];
      #pragma unroll
      for (int i=0;i<4;i++){
        int row = lg*4 + i;
        ffh[row][ncol] = f2bf(fgelu(C[i] + bi));
      }
    }
  }
  __syncthreads();

  // ---- GEMM2: [16x512]@WoT -> residual + LN2. wave w: N-tiles 2w, 2w+1 ----
  f32x4 C2[2];
  C2[0]=(f32x4){0,0,0,0}; C2[1]=(f32x4){0,0,0,0};
  for (int ks=0; ks<16; ++ks){
    s16x8 a = *reinterpret_cast<const s16x8*>(&ffh[lr][ks*32 + lg*8]);
    #pragma unroll
    for (int t2=0; t2<2; t2++){
      int ncol = (2*w+t2)*16 + lr;
      s16x8 bv = *reinterpret_cast<const s16x8*>(&woT[ncol*FFD + ks*32 + lg*8]);
      C2[t2] = __builtin_amdgcn_mfma_f32_16x16x32_bf16(a, bv, C2[t2], 0,0,0);
    }
  }
  float vv[2][4];
  float ps[4] = {0,0,0,0}, pq[4] = {0,0,0,0};
  #pragma unroll
  for (int t2=0; t2<2; t2++){
    int col = (2*w+t2)*16 + lr;
    float bo = Wob[col];
    #pragma unroll
    for (int i=0;i<4;i++){
      int row = lg*4 + i;
      float v = yL[row][col] + C2[t2][i] + bo;
      vv[t2][i] = v;
      ps[i] += v; pq[i] += v*v;
    }
  }
  #pragma unroll
  for (int i=0;i<4;i++){
    #pragma unroll
    for (int o=1;o<16;o<<=1){
      ps[i] += __shfl_xor(ps[i], o, 64);
      pq[i] += __shfl_xor(pq[i], o, 64);
    }
    if (lr == 0){ partS[lg*4+i][w] = ps[i]; partQ[lg*4+i][w] = pq[i]; }
  }
  __syncthreads();
  float mean[4], inv[4];
  #pragma unroll
  for (int i=0;i<4;i++){
    int row = lg*4 + i;
    float S = partS[row][0]+partS[row][1]+partS[row][2]+partS[row][3];
    float Q = partQ[row][0]+partQ[row][1]+partQ[row][2]+partQ[row][3];
    float m = S*(1.f/HH);
    float var = Q*(1.f/HH) - m*m;
    mean[i] = m;
    inv[i] = 1.f/sqrtf(var + 1e-5f);
  }
  #pragma unroll
  for (int t2=0; t2<2; t2++){
    int col = (2*w+t2)*16 + lr;
    float g2 = l2g[col], b2 = l2b[col];
    #pragma unroll
    for (int i=0;i<4;i++){
      int row = lg*4 + i;
      out[(size_t)(base+row)*HH + col] = (vv[t2][i]-mean[i])*inv[i]*g2 + b2;
    }
  }
}

extern "C" void kernel_launch(void* const* d_in, const int* in_sizes, int n_in,
                              void* d_out, int out_size, void* d_ws, size_t ws_size,
                              hipStream_t stream) {
  (void)in_sizes; (void)n_in; (void)out_size; (void)ws_size;
  const float* X   = (const float*)d_in[0];
  const int*   Ei  = (const int*)  d_in[1];
  const float* Wv  = (const float*)d_in[2];
  const float* Wvb = (const float*)d_in[3];
  const float* We  = (const float*)d_in[4];
  const float* Web = (const float*)d_in[5];
  const float* W1  = (const float*)d_in[6];
  const float* W1b = (const float*)d_in[7];
  const float* W2  = (const float*)d_in[8];
  const float* W2b = (const float*)d_in[9];
  const float* W3  = (const float*)d_in[10];
  const float* W3b = (const float*)d_in[11];
  const float* Wi  = (const float*)d_in[12];
  const float* Wib = (const float*)d_in[13];
  const float* Wo  = (const float*)d_in[14];
  const float* Wob = (const float*)d_in[15];
  const float* l1g = (const float*)d_in[16];
  const float* l1b = (const float*)d_in[17];
  const float* l2g = (const float*)d_in[18];
  const float* l2b = (const float*)d_in[19];
  float* out = (float*)d_out;

  float* wsf    = (float*)d_ws;
  float* featws = wsf + 0;        // 172032
  float* Qws    = wsf + 172032;   // 73728
  float* hVws   = wsf + 245760;   // 1048576
  float* Gws    = wsf + 1294336;  // 1048576
  float* Sws    = wsf + 2342912;  // 1048576 (aliased as xpre)
  float* xprews = Sws;
  float* Wfold  = wsf + 3391488;  // 2048
  float* bfold  = wsf + 3393536;  // 128
  short* w2t    = (short*)(wsf + 3393664);  // 16384 bf16 -> 8192 floats
  short* w1aT   = (short*)(wsf + 3401856);  // 16384 bf16 -> 8192
  short* w1cT   = (short*)(wsf + 3410048);  // 16384 bf16 -> 8192
  short* wiT    = (short*)(wsf + 3418240);  // 65536 bf16 -> 32768
  short* woT    = (short*)(wsf + 3451008);  // 65536 bf16 -> 32768 (end 3483776 ~13.9 MB)

  k_geom<<<dim3(64),   dim3(128), 0, stream>>>(X, Qws, featws);
  k_fold<<<dim3(713),  dim3(256), 0, stream>>>(We, Web, W1, W2, Wi, Wo,
                                               Wfold, bfold, w2t, w1aT, w1cT, wiT, woT);
  k_pre <<<dim3(BB*NN/PNB), dim3(256), 0, stream>>>(featws, Wv, Wvb, w1aT, w1cT,
                                                    W1b, bfold, hVws, Sws, Gws);
  k_msg <<<dim3(BB*NN/NPB), dim3(256), 0, stream>>>(X, Ei, Qws, Sws, Gws, hVws,
                                                    Wfold, w2t, W2b, W3, W3b, xprews);
  k_ffn <<<dim3(BB*NN/FNB), dim3(256), 0, stream>>>(xprews, wiT, woT, Wib, Wob,
                                                    l1g, l1b, l2g, l2b, out);
}

// Round 6
// 202.467 us; speedup vs baseline: 5.4308x; 1.0515x over previous
//
#include <hip/hip_runtime.h>
#include <math.h>

#define BB 4
#define NN 2048
#define KNB 30
#define HH 128
#define FFD 512

typedef __attribute__((ext_vector_type(4))) float  f32x4;
typedef __attribute__((ext_vector_type(8))) short  s16x8;
typedef __attribute__((ext_vector_type(4))) short  s16x4;

struct F3 { float x,y,z; };
__device__ __forceinline__ F3 f3(float a,float b,float c){ F3 r; r.x=a; r.y=b; r.z=c; return r; }
__device__ __forceinline__ F3 sub3(F3 a, F3 b){ return f3(a.x-b.x, a.y-b.y, a.z-b.z); }
__device__ __forceinline__ float dot3(F3 a, F3 b){ return a.x*b.x + a.y*b.y + a.z*b.z; }
__device__ __forceinline__ F3 cross3(F3 a, F3 b){
  return f3(a.y*b.z-a.z*b.y, a.z*b.x-a.x*b.z, a.x*b.y-a.y*b.x);
}
__device__ __forceinline__ F3 nrm3(F3 a){
  float n2 = dot3(a,a);
  if (n2 <= 0.f) return f3(0.f,0.f,0.f);
  float inv = 1.0f/sqrtf(n2);
  return f3(a.x*inv, a.y*inv, a.z*inv);
}
__device__ __forceinline__ float sgnf(float x){ return (x>0.f)?1.f:((x<0.f)?-1.f:0.f); }
__device__ __forceinline__ float clip1(float x){
  const float e = 1e-7f;
  return fminf(fmaxf(x, -1.f+e), 1.f-e);
}
// tanh-gelu: x * 1/(1+exp2(t*x)), t = -2.3023 - 0.10296*x^2  (folded constants)
__device__ __forceinline__ float fgelu(float x){
  float x2 = x*x;
  float t = __builtin_fmaf(-0.1029641763f, x2, -2.302344055f);
  float d = 1.f + __builtin_amdgcn_exp2f(t*x);
  return x * __builtin_amdgcn_rcpf(d);
}
// f32 -> bf16 bits, RNE
__device__ __forceinline__ short f2bf(float x){
  union { float f; unsigned u; } v; v.f = x;
  unsigned r = v.u + 0x7fffu + ((v.u >> 16) & 1u);
  return (short)(r >> 16);
}

// ---------------- K_init: geometry (blocks 0..31) + weight prep (blocks 32..744) ----------------
__global__ void k_init(const float* __restrict__ X, float* __restrict__ Qws,
                       float* __restrict__ featws,
                       const float* __restrict__ We, const float* __restrict__ Web,
                       const float* __restrict__ W1, const float* __restrict__ W2,
                       const float* __restrict__ Wi, const float* __restrict__ Wo,
                       short* __restrict__ wfoldT, float* __restrict__ bfold,
                       short* __restrict__ w2t, short* __restrict__ w1aT,
                       short* __restrict__ w1cT, short* __restrict__ wiT,
                       short* __restrict__ woT){
  if (blockIdx.x < 32){
    int t = blockIdx.x*256 + threadIdx.x;     // 0..8191
    int b = t / NN, n = t % NN;
    const float* Xb = X + (size_t)b*NN*12;
    #define LD3(r,a) f3(Xb[((r)*4+(a))*3+0], Xb[((r)*4+(a))*3+1], Xb[((r)*4+(a))*3+2])
    F3 x0=LD3(n,0), x1=LD3(n,1), x2=LD3(n,2), x3=LD3(n,3);
    F3 U[5];
    U[1]=nrm3(sub3(x1,x0));
    U[2]=nrm3(sub3(x2,x1));
    if (n>0){ F3 p = LD3(n-1,2); U[0]=nrm3(sub3(x0,p)); } else U[0]=f3(0.f,0.f,0.f);
    if (n<NN-1){ F3 y0=LD3(n+1,0), y1=LD3(n+1,1); U[3]=nrm3(sub3(y0,x2)); U[4]=nrm3(sub3(y1,y0)); }
    else { U[3]=f3(0.f,0.f,0.f); U[4]=f3(0.f,0.f,0.f); }

    float feat[21];
    #pragma unroll
    for (int tt=0; tt<3; tt++){
      bool valid = (n>0 || tt>0) && (n<NN-1 || tt==0);
      if (valid){
        F3 a=U[tt], bv=U[tt+1], c=U[tt+2];
        F3 n0=nrm3(cross3(a,bv)), n1=nrm3(cross3(bv,c));
        float cd = clip1(dot3(n0,n1));
        F3 v = nrm3(cross3(n0,n1));
        float s = sgnf(-dot3(v,bv));
        feat[tt]   = (s==0.f) ? 1.f : cd;
        feat[3+tt] = s*sqrtf(fmaxf(1.f-cd*cd, 0.f));
        float ca = clip1(dot3(a,bv));
        feat[6+tt] = ca;
        feat[9+tt] = sqrtf(fmaxf(1.f-ca*ca, 0.f));
      } else {
        feat[tt]=1.f; feat[3+tt]=0.f; feat[6+tt]=1.f; feat[9+tt]=0.f;
      }
    }
    float Q[9];
    if (n<NN-1){
      F3 b1=nrm3(sub3(U[1],U[2]));
      F3 n0=nrm3(cross3(U[1],U[2]));
      F3 r2=cross3(b1,n0);
      Q[0]=b1.x;Q[1]=b1.y;Q[2]=b1.z;Q[3]=n0.x;Q[4]=n0.y;Q[5]=n0.z;Q[6]=r2.x;Q[7]=r2.y;Q[8]=r2.z;
    } else {
      #pragma unroll
      for (int i=0;i<9;i++) Q[i]=0.f;
    }
    float* qp = Qws + (size_t)t*9;
    #pragma unroll
    for (int i=0;i<9;i++) qp[i]=Q[i];

    feat[12]=0.f; feat[13]=0.f; feat[14]=0.f;
    F3 d1=sub3(x2,x0), d2=sub3(x3,x0);
    F3 r1 = nrm3(f3(Q[0]*d1.x+Q[1]*d1.y+Q[2]*d1.z,
                    Q[3]*d1.x+Q[4]*d1.y+Q[5]*d1.z,
                    Q[6]*d1.x+Q[7]*d1.y+Q[8]*d1.z));
    F3 r2v= nrm3(f3(Q[0]*d2.x+Q[1]*d2.y+Q[2]*d2.z,
                    Q[3]*d2.x+Q[4]*d2.y+Q[5]*d2.z,
                    Q[6]*d2.x+Q[7]*d2.y+Q[8]*d2.z));
    feat[15]=r1.x; feat[16]=r1.y; feat[17]=r1.z;
    feat[18]=r2v.x; feat[19]=r2v.y; feat[20]=r2v.z;
    float* fp = featws + (size_t)t*21;
    #pragma unroll
    for (int i=0;i<21;i++) fp[i]=feat[i];
    #undef LD3
    return;
  }
  int t = (blockIdx.x-32)*256 + threadIdx.x;
  if (t < 2048){
    // wfoldT[c][j] = (We @ W1mid)[j][c], bf16
    int c = t >> 4, j = t & 15;
    float a = 0.f;
    for (int k=0;k<HH;k++) a += We[j*HH+k]*W1[(HH+k)*HH + c];
    wfoldT[t] = f2bf(a);
  } else if (t < 2176){
    int c = t - 2048;
    float a = 0.f;
    for (int k=0;k<HH;k++) a += Web[k]*W1[(HH+k)*HH + c];
    bfold[c] = a;
  } else if (t < 18560){
    int i = t - 2176;  int n = i >> 7, k = i & 127;
    w2t[n*HH + k] = f2bf(W2[k*HH + n]);
  } else if (t < 34944){
    int i = t - 18560; int n = i >> 7, k = i & 127;
    w1aT[n*HH + k] = f2bf(W1[k*HH + n]);
  } else if (t < 51328){
    int i = t - 34944; int n = i >> 7, k = i & 127;
    w1cT[n*HH + k] = f2bf(W1[(256+k)*HH + n]);
  } else if (t < 116864){
    int i = t - 51328; int n = i >> 7, k = i & 127;   // n 0..511
    wiT[n*HH + k] = f2bf(Wi[k*FFD + n]);
  } else if (t < 182400){
    int i = t - 116864; int k = i >> 7, n = i & 127;  // k 0..511
    woT[n*FFD + k] = f2bf(Wo[k*HH + n]);
  }
}

// ---- K_pre: hV (VALU K=21); S = hV@W1a + b1 + bfold, G = hV@W1c (MFMA) ----
#define PNB 32
__global__ void k_pre(const float* __restrict__ featws, const float* __restrict__ Wv,
                      const float* __restrict__ Wvb, const short* __restrict__ w1aT,
                      const short* __restrict__ w1cT, const float* __restrict__ W1b,
                      const float* __restrict__ bfold, float* __restrict__ hVws,
                      float* __restrict__ Sws, float* __restrict__ Gws){
  __shared__ __align__(16) short hvL[PNB][136];   // bf16, 272B rows
  int tid = threadIdx.x;
  int base = blockIdx.x*PNB;
  {
    int c = tid & 127, half = tid >> 7;
    float wv[21];
    #pragma unroll
    for (int j=0;j<21;j++) wv[j] = Wv[j*HH + c];
    float wb = Wvb[c];
    #pragma unroll 2
    for (int it=0; it<16; ++it){
      int g = it*2 + half;
      const float* f = featws + (size_t)(base+g)*21;
      float a = wb;
      #pragma unroll
      for (int j=0;j<21;j++) a += f[j]*wv[j];
      hVws[(size_t)(base+g)*HH + c] = a;
      hvL[g][c] = f2bf(a);
    }
  }
  __syncthreads();
  {
    int l = tid & 63, w = tid >> 6;
    int lr = l & 15, lg = l >> 4;
    int m = w & 1;
    int nbase = (w >> 1)*4;
    s16x8 afr[4];
    #pragma unroll
    for (int ks=0; ks<4; ks++)
      afr[ks] = *reinterpret_cast<const s16x8*>(&hvL[m*16 + lr][ks*32 + lg*8]);
    f32x4 Cs[4], Cg[4];
    #pragma unroll
    for (int q=0;q<4;q++){ Cs[q]=(f32x4){0,0,0,0}; Cg[q]=(f32x4){0,0,0,0}; }
    #pragma unroll
    for (int q=0;q<4;q++){
      int ncol = (nbase+q)*16 + lr;
      #pragma unroll
      for (int ks=0; ks<4; ks++){
        s16x8 ba = *reinterpret_cast<const s16x8*>(&w1aT[ncol*HH + ks*32 + lg*8]);
        s16x8 bc = *reinterpret_cast<const s16x8*>(&w1cT[ncol*HH + ks*32 + lg*8]);
        Cs[q] = __builtin_amdgcn_mfma_f32_16x16x32_bf16(afr[ks], ba, Cs[q], 0,0,0);
        Cg[q] = __builtin_amdgcn_mfma_f32_16x16x32_bf16(afr[ks], bc, Cg[q], 0,0,0);
      }
    }
    #pragma unroll
    for (int q=0;q<4;q++){
      int ncol = (nbase+q)*16 + lr;
      float bc = W1b[ncol] + bfold[ncol];
      #pragma unroll
      for (int i=0;i<4;i++){
        int row = m*16 + lg*4 + i;
        size_t o = (size_t)(base+row)*HH + ncol;
        Sws[o] = Cs[q][i] + bc;
        Gws[o] = Cg[q][i];
      }
    }
  }
}

// ---------------- K_msg: edges + layer1 (MFMA K=16pad32) + layer2 (MFMA) + colsum + W3 ----------------
#define NPB 4            // nodes per block
#define A2STR 136        // bf16 row stride (272 B)
#define EFSTR 20         // bf16 edge-feature row stride (40 B)
__launch_bounds__(256, 4)
__global__ void k_msg(const float* __restrict__ X, const int* __restrict__ Eidx,
                      const float* __restrict__ Qws, const float* __restrict__ Sws,
                      const float* __restrict__ Gws, const float* __restrict__ hVws,
                      const short* __restrict__ wfoldT, const short* __restrict__ w2t,
                      const float* __restrict__ W2b, const float* __restrict__ W3,
                      const float* __restrict__ W3b, float* __restrict__ xpre){
  __shared__ __align__(16) short efL[128*EFSTR]; // edge features bf16; csL aliases this after layer-1
  __shared__ int idxL[128];
  __shared__ __align__(16) short A2s[128*A2STR]; // m1 bf16, padded rows
  float* csL = (float*)efL;                      // 2048 B needed, 5120 B available

  const int tid = threadIdx.x;
  const int gbase = blockIdx.x*NPB;
  const int b = gbase >> 11;
  const int bofs = b*NN;

  // ---- edge geometry: threads 0..119, one edge each; 120..127 init pad slots ----
  if (tid < NPB*KNB){
    int nn = tid / KNB;
    int kk = tid - nn*KNB;
    int gnode = gbase + nn;
    int n = gnode - bofs;
    int j = Eidx[(size_t)gnode*KNB + kk];
    int r = nn*32 + kk;
    idxL[r] = j;
    const float* Qs = Qws + (size_t)gnode*9;
    float q[9];
    #pragma unroll
    for (int i=0;i<9;i++) q[i]=Qs[i];
    const float* Xb = X + (size_t)b*NN*12;
    F3 Xa = f3(Xb[n*12+0], Xb[n*12+1], Xb[n*12+2]);
    const float* Xn = Xb + (size_t)j*12;
    F3 A[4];
    A[0] = f3(Xn[3],  Xn[4],  Xn[5]);
    A[1] = f3(Xn[0],  Xn[1],  Xn[2]);
    A[2] = f3(Xn[6],  Xn[7],  Xn[8]);
    A[3] = f3(Xn[9],  Xn[10], Xn[11]);
    #pragma unroll
    for (int a=0;a<4;a++){
      F3 d = sub3(A[a], Xa);
      F3 w = f3(q[0]*d.x+q[1]*d.y+q[2]*d.z,
                q[3]*d.x+q[4]*d.y+q[5]*d.z,
                q[6]*d.x+q[7]*d.y+q[8]*d.z);
      F3 wn = nrm3(w);
      efL[r*EFSTR + a*3 + 0] = f2bf(wn.x);
      efL[r*EFSTR + a*3 + 1] = f2bf(wn.y);
      efL[r*EFSTR + a*3 + 2] = f2bf(wn.z);
    }
    const float* Qn = Qws + (size_t)(bofs + j)*9;
    float p[9];
    #pragma unroll
    for (int i=0;i<9;i++) p[i]=Qn[i];
    float R00=q[0]*p[0]+q[3]*p[3]+q[6]*p[6];
    float R01=q[0]*p[1]+q[3]*p[4]+q[6]*p[7];
    float R02=q[0]*p[2]+q[3]*p[5]+q[6]*p[8];
    float R10=q[1]*p[0]+q[4]*p[3]+q[7]*p[6];
    float R11=q[1]*p[1]+q[4]*p[4]+q[7]*p[7];
    float R12=q[1]*p[2]+q[4]*p[5]+q[7]*p[8];
    float R20=q[2]*p[0]+q[5]*p[3]+q[8]*p[6];
    float R21=q[2]*p[1]+q[5]*p[4]+q[8]*p[7];
    float R22=q[2]*p[2]+q[5]*p[5]+q[8]*p[8];
    float mx = 0.5f*sqrtf(fabsf(1.f+R00-R11-R22));
    float my = 0.5f*sqrtf(fabsf(1.f-R00+R11-R22));
    float mz = 0.5f*sqrtf(fabsf(1.f-R00-R11+R22));
    float qx = sgnf(R21-R12)*mx;
    float qy = sgnf(R02-R20)*my;
    float qz = sgnf(R10-R01)*mz;
    float qw = 0.5f*sqrtf(fmaxf(1.f+R00+R11+R22, 0.f));
    float n2 = qx*qx+qy*qy+qz*qz+qw*qw;
    float inv = (n2>0.f) ? 1.f/sqrtf(n2) : 0.f;
    efL[r*EFSTR+12]=f2bf(qx*inv); efL[r*EFSTR+13]=f2bf(qy*inv);
    efL[r*EFSTR+14]=f2bf(qz*inv); efL[r*EFSTR+15]=f2bf(qw*inv);
  } else if (tid < 128){
    int e = tid - 120;                 // 8 pad slots (nodes 0..3 x slots 30,31)
    int nn = e >> 1, slot = 30 + (e & 1);
    int r = nn*32 + slot;
    idxL[r] = 0;
    #pragma unroll
    for (int j2=0;j2<16;j2++) efL[r*EFSTR + j2] = 0;
  }
  __syncthreads();

  const int w  = tid >> 6;
  const int l  = tid & 63;
  const int lr = l & 15;
  const int lg = l >> 4;

  // ---- layer 1 via MFMA (K=16 zero-padded to 32): wave w owns node w (rows 32w..32w+31) ----
  {
    // B frags: wfoldT[col][k], k<16; lg>=2 lanes carry zeros (k 16..31)
    s16x8 bf[8];
    #pragma unroll
    for (int ct=0; ct<8; ct++){
      if (lg < 2)
        bf[ct] = *reinterpret_cast<const s16x8*>(&wfoldT[(ct*16+lr)*16 + lg*8]);
      else
        bf[ct] = (s16x8){0,0,0,0,0,0,0,0};
    }
    // A frags: efL rows of this node (2 row-tiles), two b64 loads each
    s16x8 af[2];
    #pragma unroll
    for (int rt=0; rt<2; rt++){
      if (lg < 2){
        const short* p = &efL[(w*32 + rt*16 + lr)*EFSTR + lg*8];
        s16x4 lo = *reinterpret_cast<const s16x4*>(p);
        s16x4 hi = *reinterpret_cast<const s16x4*>(p+4);
        s16x8 v;
        #pragma unroll
        for (int j2=0;j2<4;j2++){ v[j2]=lo[j2]; v[4+j2]=hi[j2]; }
        af[rt] = v;
      } else {
        af[rt] = (s16x8){0,0,0,0,0,0,0,0};
      }
    }
    // neighbor row offsets for this lane's C rows
    int goff[2][4];
    #pragma unroll
    for (int rt=0; rt<2; rt++)
      #pragma unroll
      for (int i=0;i<4;i++)
        goff[rt][i] = (bofs + idxL[w*32 + rt*16 + lg*4 + i])*HH;

    const float* Srow = Sws + (size_t)(gbase+w)*HH;
    #pragma unroll
    for (int ct=0; ct<8; ct++){
      int col = ct*16 + lr;
      float sv = Srow[col];
      #pragma unroll
      for (int rt=0; rt<2; rt++){
        f32x4 C = __builtin_amdgcn_mfma_f32_16x16x32_bf16(af[rt], bf[ct], (f32x4){0,0,0,0}, 0,0,0);
        #pragma unroll
        for (int i=0;i<4;i++){
          int slot = rt*16 + lg*4 + i;
          float g = Gws[goff[rt][i] + col];
          float v = (slot < KNB) ? fgelu(C[i] + sv + g) : 0.f;
          A2s[(w*32 + slot)*A2STR + col] = f2bf(v);
        }
      }
    }
  }
  __syncthreads();

  // ---- layer 2 (MFMA 16x16x32 bf16): wave w handles node w ----
  {
    f32x4 Cacc[2][8];
    #pragma unroll
    for (int mt=0; mt<2; mt++)
      #pragma unroll
      for (int nt=0; nt<8; nt++)
        Cacc[mt][nt] = (f32x4){0.f,0.f,0.f,0.f};
    #pragma unroll
    for (int ks=0; ks<4; ks++){
      const int koff = ks*32 + lg*8;
      s16x8 a0 = *reinterpret_cast<const s16x8*>(&A2s[(w*32      + lr)*A2STR + koff]);
      s16x8 a1 = *reinterpret_cast<const s16x8*>(&A2s[(w*32 + 16 + lr)*A2STR + koff]);
      #pragma unroll
      for (int nt=0; nt<8; nt++){
        s16x8 bv = *reinterpret_cast<const s16x8*>(&w2t[(lr + nt*16)*HH + koff]);
        Cacc[0][nt] = __builtin_amdgcn_mfma_f32_16x16x32_bf16(a0, bv, Cacc[0][nt], 0,0,0);
        Cacc[1][nt] = __builtin_amdgcn_mfma_f32_16x16x32_bf16(a1, bv, Cacc[1][nt], 0,0,0);
      }
    }
    #pragma unroll
    for (int nt=0; nt<8; nt++){
      float b2v = W2b[lr + nt*16];
      float part = 0.f;
      #pragma unroll
      for (int mt=0; mt<2; mt++){
        #pragma unroll
        for (int i=0; i<4; i++){
          int row32 = mt*16 + lg*4 + i;
          float v = fgelu(Cacc[mt][nt][i] + b2v);
          if (row32 < KNB) part += v;
        }
      }
      part += __shfl_xor(part, 16, 64);
      part += __shfl_xor(part, 32, 64);
      if (l < 16) csL[w*HH + nt*16 + lr] = part;
    }
  }
  __syncthreads();

  // ---- dh = colsum @ W3 / 30 + b3; xpre = hV + dh ----
  {
    const int h = tid & 127;
    const int half = tid >> 7;
    #pragma unroll
    for (int q2=0; q2<2; q2++){
      int nn = half*2 + q2;
      const float* cs = csL + nn*HH;
      float acc = 0.f;
      for (int j=0;j<HH;j+=4){
        acc += cs[j]  *W3[(j  )*HH+h] + cs[j+1]*W3[(j+1)*HH+h]
             + cs[j+2]*W3[(j+2)*HH+h] + cs[j+3]*W3[(j+3)*HH+h];
      }
      size_t o = (size_t)(gbase + nn)*HH + h;
      xpre[o] = hVws[o] + acc*(1.f/30.f) + W3b[h];
    }
  }
}

// ---------------- K4: LN1 + FFN (MFMA) + LN2, 16 nodes per block, 4 waves ----------------
#define FNB 16
__global__ void k_ffn(const float* __restrict__ xpre, const short* __restrict__ wiT,
                      const short* __restrict__ woT, const float* __restrict__ Wib,
                      const float* __restrict__ Wob, const float* __restrict__ l1g,
                      const float* __restrict__ l1b, const float* __restrict__ l2g,
                      const float* __restrict__ l2b, float* __restrict__ out){
  __shared__ __align__(16) short hv1[FNB][136];   // bf16 LN1 out
  __shared__ __align__(16) float yL[FNB][HH];     // f32 LN1 out (residual)
  __shared__ __align__(16) short ffh[FNB][520];   // bf16 gelu(ffn1)
  __shared__ float partS[FNB][4], partQ[FNB][4];
  const int tid = threadIdx.x;
  const int l = tid & 63, w = tid >> 6;
  const int base = blockIdx.x*FNB;

  #pragma unroll
  for (int ri=0; ri<4; ri++){
    int r = w*4 + ri;
    const float* xp = xpre + (size_t)(base+r)*HH;
    float x0 = xp[l], x1 = xp[l+64];
    float s = x0 + x1;
    #pragma unroll
    for (int o=32;o>0;o>>=1) s += __shfl_xor(s, o, 64);
    float mean = s*(1.f/HH);
    float d0 = x0-mean, d1 = x1-mean;
    float q = d0*d0 + d1*d1;
    #pragma unroll
    for (int o=32;o>0;o>>=1) q += __shfl_xor(q, o, 64);
    float inv = 1.f/sqrtf(q*(1.f/HH) + 1e-5f);
    float y0 = d0*inv*l1g[l]    + l1b[l];
    float y1 = d1*inv*l1g[l+64] + l1b[l+64];
    yL[r][l] = y0; yL[r][l+64] = y1;
    hv1[r][l] = f2bf(y0); hv1[r][l+64] = f2bf(y1);
  }
  __syncthreads();

  const int lr = l & 15, lg = l >> 4;
  {
    s16x8 afr[4];
    #pragma unroll
    for (int ks=0; ks<4; ks++)
      afr[ks] = *reinterpret_cast<const s16x8*>(&hv1[lr][ks*32 + lg*8]);
    #pragma unroll
    for (int q=0; q<8; q++){
      int ncol = (w*8+q)*16 + lr;
      f32x4 C = (f32x4){0,0,0,0};
      #pragma unroll
      for (int ks=0; ks<4; ks++){
        s16x8 bv = *reinterpret_cast<const s16x8*>(&wiT[ncol*HH + ks*32 + lg*8]);
        C = __builtin_amdgcn_mfma_f32_16x16x32_bf16(afr[ks], bv, C, 0,0,0);
      }
      float bi = Wib[ncol];
      #pragma unroll
      for (int i=0;i<4;i++){
        int row = lg*4 + i;
        ffh[row][ncol] = f2bf(fgelu(C[i] + bi));
      }
    }
  }
  __syncthreads();

  f32x4 C2[2];
  C2[0]=(f32x4){0,0,0,0}; C2[1]=(f32x4){0,0,0,0};
  for (int ks=0; ks<16; ++ks){
    s16x8 a = *reinterpret_cast<const s16x8*>(&ffh[lr][ks*32 + lg*8]);
    #pragma unroll
    for (int t2=0; t2<2; t2++){
      int ncol = (2*w+t2)*16 + lr;
      s16x8 bv = *reinterpret_cast<const s16x8*>(&woT[ncol*FFD + ks*32 + lg*8]);
      C2[t2] = __builtin_amdgcn_mfma_f32_16x16x32_bf16(a, bv, C2[t2], 0,0,0);
    }
  }
  float vv[2][4];
  float ps[4] = {0,0,0,0}, pq[4] = {0,0,0,0};
  #pragma unroll
  for (int t2=0; t2<2; t2++){
    int col = (2*w+t2)*16 + lr;
    float bo = Wob[col];
    #pragma unroll
    for (int i=0;i<4;i++){
      int row = lg*4 + i;
      float v = yL[row][col] + C2[t2][i] + bo;
      vv[t2][i] = v;
      ps[i] += v; pq[i] += v*v;
    }
  }
  #pragma unroll
  for (int i=0;i<4;i++){
    #pragma unroll
    for (int o=1;o<16;o<<=1){
      ps[i] += __shfl_xor(ps[i], o, 64);
      pq[i] += __shfl_xor(pq[i], o, 64);
    }
    if (lr == 0){ partS[lg*4+i][w] = ps[i]; partQ[lg*4+i][w] = pq[i]; }
  }
  __syncthreads();
  float mean[4], inv[4];
  #pragma unroll
  for (int i=0;i<4;i++){
    int row = lg*4 + i;
    float S = partS[row][0]+partS[row][1]+partS[row][2]+partS[row][3];
    float Q = partQ[row][0]+partQ[row][1]+partQ[row][2]+partQ[row][3];
    float m = S*(1.f/HH);
    float var = Q*(1.f/HH) - m*m;
    mean[i] = m;
    inv[i] = 1.f/sqrtf(var + 1e-5f);
  }
  #pragma unroll
  for (int t2=0; t2<2; t2++){
    int col = (2*w+t2)*16 + lr;
    float g2 = l2g[col], b2 = l2b[col];
    #pragma unroll
    for (int i=0;i<4;i++){
      int row = lg*4 + i;
      out[(size_t)(base+row)*HH + col] = (vv[t2][i]-mean[i])*inv[i]*g2 + b2;
    }
  }
}

extern "C" void kernel_launch(void* const* d_in, const int* in_sizes, int n_in,
                              void* d_out, int out_size, void* d_ws, size_t ws_size,
                              hipStream_t stream) {
  (void)in_sizes; (void)n_in; (void)out_size; (void)ws_size;
  const float* X   = (const float*)d_in[0];
  const int*   Ei  = (const int*)  d_in[1];
  const float* Wv  = (const float*)d_in[2];
  const float* Wvb = (const float*)d_in[3];
  const float* We  = (const float*)d_in[4];
  const float* Web = (const float*)d_in[5];
  const float* W1  = (const float*)d_in[6];
  const float* W1b = (const float*)d_in[7];
  const float* W2  = (const float*)d_in[8];
  const float* W2b = (const float*)d_in[9];
  const float* W3  = (const float*)d_in[10];
  const float* W3b = (const float*)d_in[11];
  const float* Wi  = (const float*)d_in[12];
  const float* Wib = (const float*)d_in[13];
  const float* Wo  = (const float*)d_in[14];
  const float* Wob = (const float*)d_in[15];
  const float* l1g = (const float*)d_in[16];
  const float* l1b = (const float*)d_in[17];
  const float* l2g = (const float*)d_in[18];
  const float* l2b = (const float*)d_in[19];
  float* out = (float*)d_out;

  float* wsf    = (float*)d_ws;
  float* featws = wsf + 0;        // 172032
  float* Qws    = wsf + 172032;   // 73728
  float* hVws   = wsf + 245760;   // 1048576
  float* Gws    = wsf + 1294336;  // 1048576
  float* Sws    = wsf + 2342912;  // 1048576 (aliased as xpre; each block reads own S rows
                                  //          in layer-1 before writing same rows in phase 3)
  float* xprews = Sws;
  short* wfoldT = (short*)(wsf + 3391488);  // 2048 bf16 -> 1024 floats
  float* bfold  = wsf + 3392512;            // 128
  short* w2t    = (short*)(wsf + 3392640);  // 16384 bf16 -> 8192 floats
  short* w1aT   = (short*)(wsf + 3400832);  // 8192
  short* w1cT   = (short*)(wsf + 3409024);  // 8192
  short* wiT    = (short*)(wsf + 3417216);  // 32768
  short* woT    = (short*)(wsf + 3449984);  // 32768 (end 3482752 ~13.9 MB)

  k_init<<<dim3(745), dim3(256), 0, stream>>>(X, Qws, featws, We, Web, W1, W2, Wi, Wo,
                                              wfoldT, bfold, w2t, w1aT, w1cT, wiT, woT);
  k_pre <<<dim3(BB*NN/PNB), dim3(256), 0, stream>>>(featws, Wv, Wvb, w1aT, w1cT,
                                                    W1b, bfold, hVws, Sws, Gws);
  k_msg <<<dim3(BB*NN/NPB), dim3(256), 0, stream>>>(X, Ei, Qws, Sws, Gws, hVws,
                                                    wfoldT, w2t, W2b, W3, W3b, xprews);
  k_ffn <<<dim3(BB*NN/FNB), dim3(256), 0, stream>>>(xprews, wiT, woT, Wib, Wob,
                                                    l1g, l1b, l2g, l2b, out);
}